// Round 6
// baseline (2408.469 us; speedup 1.0000x reference)
//
#include <hip/hip_runtime.h>
#include <math.h>

// Problem constants (match reference)
constexpr int N = 10000, E = 100000, G = 64;
constexpr int F = 64, Dk = 256, L = 3;
constexpr int HID = 256, NCLS = 10;

__device__ __forceinline__ float sigmoidf_(float x) {
    return 1.0f / (1.0f + __expf(-x));
}
__device__ __forceinline__ float leakyf_(float v) {
    return v > 0.0f ? v : 0.01f * v;
}

#define FMA4X4(aa, w0, w1, w2, w3, acc_)                                      \
    acc_.x = fmaf(aa.x, w0.x, acc_.x); acc_.y = fmaf(aa.x, w0.y, acc_.y);     \
    acc_.z = fmaf(aa.x, w0.z, acc_.z); acc_.w = fmaf(aa.x, w0.w, acc_.w);     \
    acc_.x = fmaf(aa.y, w1.x, acc_.x); acc_.y = fmaf(aa.y, w1.y, acc_.y);     \
    acc_.z = fmaf(aa.y, w1.z, acc_.z); acc_.w = fmaf(aa.y, w1.w, acc_.w);     \
    acc_.x = fmaf(aa.z, w2.x, acc_.x); acc_.y = fmaf(aa.z, w2.y, acc_.y);     \
    acc_.z = fmaf(aa.z, w2.z, acc_.z); acc_.w = fmaf(aa.z, w2.w, acc_.w);     \
    acc_.x = fmaf(aa.w, w3.x, acc_.x); acc_.y = fmaf(aa.w, w3.y, acc_.y);     \
    acc_.z = fmaf(aa.w, w3.z, acc_.z); acc_.w = fmaf(aa.w, w3.w, acc_.w);

// ---------------------------------------------------------------------------
// Edge sort by dst: histogram -> single-block scan -> scatter.
// ---------------------------------------------------------------------------
__global__ void k_hist(const int* __restrict__ ei, int* __restrict__ deg) {
    const int e = blockIdx.x * 256 + threadIdx.x;
    if (e < E) atomicAdd(&deg[ei[E + e]], 1);
}

__global__ void k_scan(const int* __restrict__ deg, int* __restrict__ cursor) {
    __shared__ int part[256];
    __shared__ int off[256];
    const int t = threadIdx.x;
    const int base = t * 40;  // 256*40 = 10240 >= N
    int s = 0;
    for (int i = 0; i < 40; ++i) {
        const int idx = base + i;
        if (idx < N) s += deg[idx];
    }
    part[t] = s;
    __syncthreads();
    if (t == 0) {
        int acc = 0;
        for (int i = 0; i < 256; ++i) { off[i] = acc; acc += part[i]; }
    }
    __syncthreads();
    int run = off[t];
    for (int i = 0; i < 40; ++i) {
        const int idx = base + i;
        if (idx < N) { cursor[idx] = run; run += deg[idx]; }
    }
}

__global__ void k_scatter(const int* __restrict__ ei, const int* __restrict__ batch,
                          int* __restrict__ cursor, int* __restrict__ src_s,
                          int* __restrict__ dst_s, int* __restrict__ gb_s,
                          int* __restrict__ eperm) {
    const int e = blockIdx.x * 256 + threadIdx.x;
    if (e < E) {
        const int d = ei[E + e];
        const int pos = atomicAdd(&cursor[d], 1);
        dst_s[pos] = d;
        src_s[pos] = ei[e];
        gb_s[pos] = batch[d];
        eperm[pos] = e;
    }
}

// ---------------------------------------------------------------------------
// Fused edge kernel (edges pre-sorted by dst), 16-rows-per-thread retile:
//   h1  = leaky(xa[dst] + xb[src] + gfc[batch[dst]])   (gfc includes b1)
//   msg = leaky(h1 @ W2 + b2)
//   gp  = msg @ Wg + bg ; lw = sigmoid(gp)*msg
//   lgl[eperm[e], layer] = ||lw|| ; nxt[dst] += lw*msg (segmented atomics)
// Block: 128 thr = 2 waves. 32 edges/block. Wave wv owns cols [wv*128,+128).
// Lane: rh = lane>>5 picks 16-row half; c0 = wv*128 + (lane&31)*4.
// Thread tile = 16 rows x 4 cols (acc float4[16]) -> 8 FLOP per W-byte,
// 2x the arithmetic intensity of the 8-row version (W-L1 pressure halved).
// ---------------------------------------------------------------------------
__global__ __launch_bounds__(128, 4) void k_edge_rt(
    const float* __restrict__ xa, const float* __restrict__ xb,
    const float* __restrict__ gfc,
    const int* __restrict__ src_s, const int* __restrict__ dst_s,
    const int* __restrict__ gb_s, const int* __restrict__ eperm,
    const float* __restrict__ W2, const float* __restrict__ b2,
    const float* __restrict__ Wg, const float* __restrict__ bg,
    float* __restrict__ nxt, float* __restrict__ lgl, int layer) {
    __shared__ float tile[32][Dk];   // h1, then msg (32 KB)
    __shared__ int sdst[32];
    __shared__ float prow[2][32];

    const int t = threadIdx.x;
    // bijective chunked XCD swizzle: consecutive dst-ranges stay on one XCD
    constexpr int NBLK = E / 32;               // 3125
    constexpr int qq = NBLK / 8, rr = NBLK % 8;
    const int orig = blockIdx.x;
    const int xcd = orig & 7, pos = orig >> 3;
    const int bid = (xcd < rr ? xcd * (qq + 1) : rr * (qq + 1) + (xcd - rr) * qq) + pos;
    const int e0 = bid * 32;

    // ---- h1 tile: 4 threads per row, 16 float4 each ----
    {
        const int r = t >> 2, l4 = t & 3;
        const int d = dst_s[e0 + r], s = src_s[e0 + r], b = gb_s[e0 + r];
        const float4* pa = (const float4*)(xa + (size_t)d * Dk);
        const float4* pb = (const float4*)(xb + (size_t)s * Dk);
        const float4* pg = (const float4*)(gfc + (size_t)b * Dk);
        float4* pt = (float4*)(&tile[r][0]);
#pragma unroll
        for (int j = 0; j < 16; ++j) {
            const int ci = l4 + 4 * j;
            const float4 va = pa[ci], vb = pb[ci], vg = pg[ci];
            float4 v;
            v.x = leakyf_(va.x + vb.x + vg.x);
            v.y = leakyf_(va.y + vb.y + vg.y);
            v.z = leakyf_(va.z + vb.z + vg.z);
            v.w = leakyf_(va.w + vb.w + vg.w);
            pt[ci] = v;
        }
    }
    if (t < 32) sdst[t] = dst_s[e0 + t];
    __syncthreads();

    const int lane = t & 63, wv = t >> 6;
    const int rbase = (lane >> 5) * 16;              // thread's 16 rows
    const int c0 = wv * 128 + (lane & 31) * 4;       // thread's 4 cols
    float4 acc[16];

    // ============ GEMM1: msg = leaky(h1 @ W2 + b2), W from global ============
    {
        const float4 bi = *(const float4*)(b2 + c0);
#pragma unroll
        for (int e = 0; e < 16; ++e) acc[e] = bi;
    }
#pragma unroll 2
    for (int k = 0; k < Dk; k += 4) {
        const float4 w0 = *(const float4*)(W2 + (size_t)(k + 0) * Dk + c0);
        const float4 w1 = *(const float4*)(W2 + (size_t)(k + 1) * Dk + c0);
        const float4 w2 = *(const float4*)(W2 + (size_t)(k + 2) * Dk + c0);
        const float4 w3 = *(const float4*)(W2 + (size_t)(k + 3) * Dk + c0);
#pragma unroll
        for (int e = 0; e < 16; ++e) {
            const float4 a = *(const float4*)(&tile[rbase + e][k]);
            FMA4X4(a, w0, w1, w2, w3, acc[e]);
        }
    }
    __syncthreads();  // all h1 reads done before overwrite
#pragma unroll
    for (int e = 0; e < 16; ++e) {
        float4 m;
        m.x = leakyf_(acc[e].x);
        m.y = leakyf_(acc[e].y);
        m.z = leakyf_(acc[e].z);
        m.w = leakyf_(acc[e].w);
        *(float4*)(&tile[rbase + e][c0]) = m;
    }
    __syncthreads();  // msg tile complete

    // ============ GEMM2: gp = msg @ Wg + bg ============
    {
        const float4 bi = *(const float4*)(bg + c0);
#pragma unroll
        for (int e = 0; e < 16; ++e) acc[e] = bi;
    }
#pragma unroll 2
    for (int k = 0; k < Dk; k += 4) {
        const float4 w0 = *(const float4*)(Wg + (size_t)(k + 0) * Dk + c0);
        const float4 w1 = *(const float4*)(Wg + (size_t)(k + 1) * Dk + c0);
        const float4 w2 = *(const float4*)(Wg + (size_t)(k + 2) * Dk + c0);
        const float4 w3 = *(const float4*)(Wg + (size_t)(k + 3) * Dk + c0);
#pragma unroll
        for (int e = 0; e < 16; ++e) {
            const float4 a = *(const float4*)(&tile[rbase + e][k]);
            FMA4X4(a, w0, w1, w2, w3, acc[e]);
        }
    }

    // ---- epilogue: lw = sigmoid(gp)*msg; segmented scatter; row norms ----
    float4 vsum = make_float4(0.f, 0.f, 0.f, 0.f);
#pragma unroll
    for (int e = 0; e < 16; ++e) {
        const int row = rbase + e;
        const float4 m = *(const float4*)(&tile[row][c0]);
        float4 lw;
        lw.x = sigmoidf_(acc[e].x) * m.x;
        lw.y = sigmoidf_(acc[e].y) * m.y;
        lw.z = sigmoidf_(acc[e].z) * m.z;
        lw.w = sigmoidf_(acc[e].w) * m.w;
        vsum.x += lw.x * m.x;
        vsum.y += lw.y * m.y;
        vsum.z += lw.z * m.z;
        vsum.w += lw.w * m.w;
        const int d = sdst[row];
        const bool flush = (e == 15) || (sdst[row + 1] != d);
        if (flush) {
            float* base = nxt + (size_t)d * Dk + c0;
            atomicAdd(base + 0, vsum.x);
            atomicAdd(base + 1, vsum.y);
            atomicAdd(base + 2, vsum.z);
            atomicAdd(base + 3, vsum.w);
            vsum = make_float4(0.f, 0.f, 0.f, 0.f);
        }
        float s = lw.x * lw.x + lw.y * lw.y + lw.z * lw.z + lw.w * lw.w;
        s += __shfl_xor(s, 1, 64);
        s += __shfl_xor(s, 2, 64);
        s += __shfl_xor(s, 4, 64);
        s += __shfl_xor(s, 8, 64);
        s += __shfl_xor(s, 16, 64);  // sum over the 32-lane col-group (same row)
        if ((lane & 31) == 0) prow[wv][row] = s;
    }
    __syncthreads();
    if (t < 32) {
        const float s = prow[0][t] + prow[1][t];
        lgl[(size_t)eperm[e0 + t] * L + layer] = sqrtf(s);
    }
}

// ---------------------------------------------------------------------------
// Node GEMM, NW weight streams sharing one A tile (sequential passes):
//   C_w[M,256] = A[M,256] @ W_w[256,256]
// 128 thr, 32 rows/block, thread = 16 rows x 4 cols; W from global.
// ---------------------------------------------------------------------------
template <int NW>
__global__ __launch_bounds__(128, 4) void k_mm(
    const float* __restrict__ A, int M,
    const float* __restrict__ Wp0, const float* __restrict__ Wp1,
    const float* __restrict__ Wp2,
    float* __restrict__ Cp0, float* __restrict__ Cp1, float* __restrict__ Cp2) {
    __shared__ float tile[32][Dk];
    const int t = threadIdx.x;
    const int r0 = blockIdx.x * 32;
    {
        const int r = t >> 2, l4 = t & 3;
        int row = r0 + r;
        if (row >= M) row = M - 1;
        const float4* pa = (const float4*)(A + (size_t)row * Dk);
        float4* pt = (float4*)(&tile[r][0]);
#pragma unroll
        for (int j = 0; j < 16; ++j) {
            const int ci = l4 + 4 * j;
            pt[ci] = pa[ci];
        }
    }
    __syncthreads();

    const int lane = t & 63, wv = t >> 6;
    const int rbase = (lane >> 5) * 16;
    const int c0 = wv * 128 + (lane & 31) * 4;

    const float* Ws[3] = {Wp0, Wp1, Wp2};
    float* Cs[3] = {Cp0, Cp1, Cp2};
#pragma unroll
    for (int w = 0; w < NW; ++w) {
        const float* Wp = Ws[w];
        float4 acc[16];
#pragma unroll
        for (int e = 0; e < 16; ++e) acc[e] = make_float4(0.f, 0.f, 0.f, 0.f);
#pragma unroll 2
        for (int k = 0; k < Dk; k += 4) {
            const float4 w0 = *(const float4*)(Wp + (size_t)(k + 0) * Dk + c0);
            const float4 w1 = *(const float4*)(Wp + (size_t)(k + 1) * Dk + c0);
            const float4 w2 = *(const float4*)(Wp + (size_t)(k + 2) * Dk + c0);
            const float4 w3 = *(const float4*)(Wp + (size_t)(k + 3) * Dk + c0);
#pragma unroll
            for (int e = 0; e < 16; ++e) {
                const float4 a = *(const float4*)(&tile[rbase + e][k]);
                FMA4X4(a, w0, w1, w2, w3, acc[e]);
            }
        }
        float* Cp = Cs[w];
#pragma unroll
        for (int e = 0; e < 16; ++e) {
            const int row = r0 + rbase + e;
            if (row < M) *(float4*)(Cp + (size_t)row * Dk + c0) = acc[e];
        }
    }
}

// ---------------------------------------------------------------------------
// Small GEMM for G-row matrices: C[M,ncols] = A[M,256] @ B (+bias)
// ---------------------------------------------------------------------------
template <int ROWS>
__global__ void k_gemm(const float* __restrict__ A,
                       const float* __restrict__ B, int ldb,
                       const float* __restrict__ bias,
                       float* __restrict__ C, int ldc, int M) {
    __shared__ float Ald[ROWS][Dk];
    const int t = threadIdx.x;
    const int r0 = blockIdx.x * ROWS;
#pragma unroll
    for (int i = 0; i < ROWS; ++i)
        Ald[i][t] = (r0 + i < M) ? A[(size_t)(r0 + i) * Dk + t] : 0.0f;
    __syncthreads();

    const int c = blockIdx.y * 256 + t;
    float acc[ROWS];
    const float bi = bias ? bias[c] : 0.0f;
#pragma unroll
    for (int e = 0; e < ROWS; ++e) acc[e] = bi;

    for (int k = 0; k < Dk; k += 4) {
        const float w0 = B[(size_t)(k + 0) * ldb + c];
        const float w1 = B[(size_t)(k + 1) * ldb + c];
        const float w2 = B[(size_t)(k + 2) * ldb + c];
        const float w3 = B[(size_t)(k + 3) * ldb + c];
#pragma unroll
        for (int e = 0; e < ROWS; ++e) {
            const float4 a = *reinterpret_cast<const float4*>(&Ald[e][k]);
            acc[e] = fmaf(a.x, w0, acc[e]);
            acc[e] = fmaf(a.y, w1, acc[e]);
            acc[e] = fmaf(a.z, w2, acc[e]);
            acc[e] = fmaf(a.w, w3, acc[e]);
        }
    }
#pragma unroll
    for (int e = 0; e < ROWS; ++e)
        if (r0 + e < M) C[(size_t)(r0 + e) * ldc + c] = acc[e];
}

// fc: C[M,256] = A[M,64] @ B[64,256] + bias
__global__ void k_fc(const float* __restrict__ A, const float* __restrict__ B,
                     const float* __restrict__ bias, float* __restrict__ C, int M) {
    __shared__ float Ald[32][F];
    const int t = threadIdx.x;
    const int r0 = blockIdx.x * 32;
    for (int i = t; i < 32 * F; i += 256) {
        int r = i >> 6, k = i & 63;
        Ald[r][k] = (r0 + r < M) ? A[(size_t)(r0 + r) * F + k] : 0.0f;
    }
    __syncthreads();
    const int c = t;
    float acc[32];
    const float bi = bias[c];
#pragma unroll
    for (int e = 0; e < 32; ++e) acc[e] = bi;
    for (int k = 0; k < F; k += 4) {
        const float w0 = B[(size_t)(k + 0) * Dk + c];
        const float w1 = B[(size_t)(k + 1) * Dk + c];
        const float w2 = B[(size_t)(k + 2) * Dk + c];
        const float w3 = B[(size_t)(k + 3) * Dk + c];
#pragma unroll
        for (int e = 0; e < 32; ++e) {
            const float4 a = *reinterpret_cast<const float4*>(&Ald[e][k]);
            acc[e] = fmaf(a.x, w0, acc[e]);
            acc[e] = fmaf(a.y, w1, acc[e]);
            acc[e] = fmaf(a.z, w2, acc[e]);
            acc[e] = fmaf(a.w, w3, acc[e]);
        }
    }
#pragma unroll
    for (int e = 0; e < 32; ++e)
        if (r0 + e < M) C[(size_t)(r0 + e) * Dk + c] = acc[e];
}

// ---------------------------------------------------------------------------
// Readout node pass (batch sorted): run-accumulated scatter.
// ---------------------------------------------------------------------------
constexpr int RNPB = 40;  // nodes per block, 250 blocks
__global__ void k_readout_node(const float* __restrict__ x, const float* __restrict__ xr,
                               const float* __restrict__ gfr, const int* __restrict__ batch,
                               float* __restrict__ gfn, float* __restrict__ gnorm) {
    const int t = threadIdx.x;
    const int n0 = blockIdx.x * RNPB;
    {   // phase A
        const int c = t;
        float acc = 0.0f;
        int bprev = batch[n0];
        for (int i = 0; i < RNPB; ++i) {
            const int n = n0 + i;
            const int b = batch[n];
            if (b != bprev) {
                atomicAdd(&gfn[(size_t)bprev * Dk + c], acc);
                acc = 0.0f;
                bprev = b;
            }
            const float g = sigmoidf_(xr[(size_t)n * Dk + c] + gfr[(size_t)b * Dk + c]);
            acc = fmaf(g, x[(size_t)n * Dk + c], acc);
        }
        atomicAdd(&gfn[(size_t)bprev * Dk + c], acc);
    }
    {   // phase B
        const int lane = t & 63, wv = t >> 6;
        float rs = 0.0f;
        int bprev = -1;
        for (int i = wv; i < RNPB; i += 4) {
            const int n = n0 + i;
            const int b = batch[n];
            const float4 vr = *(const float4*)(xr + (size_t)n * Dk + lane * 4);
            const float4 vg = *(const float4*)(gfr + (size_t)b * Dk + lane * 4);
            const float g0 = sigmoidf_(vr.x + vg.x), g1 = sigmoidf_(vr.y + vg.y);
            const float g2 = sigmoidf_(vr.z + vg.z), g3 = sigmoidf_(vr.w + vg.w);
            float s = g0 * g0 + g1 * g1 + g2 * g2 + g3 * g3;
            s += __shfl_xor(s, 1, 64);
            s += __shfl_xor(s, 2, 64);
            s += __shfl_xor(s, 4, 64);
            s += __shfl_xor(s, 8, 64);
            s += __shfl_xor(s, 16, 64);
            s += __shfl_xor(s, 32, 64);
            if (lane == 0) {
                if (b != bprev && bprev >= 0) {
                    atomicAdd(&gnorm[bprev], rs);
                    rs = 0.0f;
                }
                bprev = b;
                rs += sqrtf(s);
            }
        }
        if (lane == 0 && bprev >= 0) atomicAdd(&gnorm[bprev], rs);
    }
}

__global__ void k_cnt(const int* __restrict__ batch, float* __restrict__ gcnt) {
    const int n = blockIdx.x * 256 + threadIdx.x;
    if (n < N) atomicAdd(&gcnt[batch[n]], 1.0f);
}

__global__ void k_ggl(const float* __restrict__ gnorm, const float* __restrict__ gcnt,
                      float* __restrict__ out) {
    const int t = threadIdx.x;  // 64 threads
    float v = gnorm[t] / fmaxf(gcnt[t], 1.0f);
#pragma unroll
    for (int off = 32; off; off >>= 1) v += __shfl_xor(v, off, 64);
    if (t == 0) *out = v * (1.0f / G);
}

// transpose in[rows,cols] -> out[cols,rows]
__global__ void k_transpose(const float* __restrict__ in, float* __restrict__ out,
                            int rows, int cols) {
    const int idx = blockIdx.x * 256 + threadIdx.x;
    if (idx < rows * cols) {
        const int r = idx / cols, c = idx % cols;
        out[(size_t)c * rows + r] = in[(size_t)r * cols + c];
    }
}

// GRU elementwise combine (gi, gh are [G,768]); gf updated in place.
__global__ void k_gru_ew(const float* __restrict__ gi, const float* __restrict__ gh,
                         float* __restrict__ gf) {
    const int g = blockIdx.x, d = threadIdx.x;
    const float* Gi = gi + (size_t)g * 768;
    const float* Gh = gh + (size_t)g * 768;
    const float h = gf[(size_t)g * Dk + d];
    const float r = sigmoidf_(Gi[d] + Gh[d]);
    const float z = sigmoidf_(Gi[256 + d] + Gh[256 + d]);
    const float nn = tanhf(Gi[512 + d] + r * Gh[512 + d]);
    gf[(size_t)g * Dk + d] = (1.0f - z) * nn + z * h;
}

// BatchNorm (training stats over G graphs) -> xn
__global__ void k_bn(const float* __restrict__ gf, const float* __restrict__ bg,
                     const float* __restrict__ bb, float* __restrict__ xn) {
    const int f = threadIdx.x;
    float mu = 0.0f;
    for (int g = 0; g < G; ++g) mu += gf[(size_t)g * Dk + f];
    mu *= (1.0f / G);
    float var = 0.0f;
    for (int g = 0; g < G; ++g) {
        const float d = gf[(size_t)g * Dk + f] - mu;
        var += d * d;
    }
    var *= (1.0f / G);
    const float inv = (1.0f / sqrtf(var + 1e-5f)) * bg[f];
    const float bet = bb[f];
    for (int g = 0; g < G; ++g)
        xn[(size_t)g * Dk + f] = (gf[(size_t)g * Dk + f] - mu) * inv + bet;
}

__global__ void k_clf1(const float* __restrict__ xn, const float* __restrict__ W,
                       const float* __restrict__ b, float* __restrict__ out) {
    __shared__ float row[Dk];
    const int g = blockIdx.x, t = threadIdx.x;
    row[t] = xn[(size_t)g * Dk + t];
    __syncthreads();
    float acc = b[t];
    for (int k = 0; k < Dk; k += 4) {
        const float4 a = *reinterpret_cast<const float4*>(&row[k]);
        acc = fmaf(a.x, W[(size_t)(k + 0) * HID + t], acc);
        acc = fmaf(a.y, W[(size_t)(k + 1) * HID + t], acc);
        acc = fmaf(a.z, W[(size_t)(k + 2) * HID + t], acc);
        acc = fmaf(a.w, W[(size_t)(k + 3) * HID + t], acc);
    }
    out[(size_t)g * HID + t] = leakyf_(acc);
}

__global__ void k_clf2(const float* __restrict__ h, const float* __restrict__ W,
                       const float* __restrict__ b, float* __restrict__ out) {
    __shared__ float row[HID];
    __shared__ float lg[NCLS];
    const int g = blockIdx.x, t = threadIdx.x;
    row[t] = h[(size_t)g * HID + t];
    __syncthreads();
    if (t < NCLS) {
        float acc = b[t];
        for (int k = 0; k < HID; ++k) acc = fmaf(row[k], W[(size_t)k * NCLS + t], acc);
        lg[t] = acc;
    }
    __syncthreads();
    if (t == 0) {
        float m = lg[0];
        for (int i = 1; i < NCLS; ++i) m = fmaxf(m, lg[i]);
        float s = 0.0f;
        for (int i = 0; i < NCLS; ++i) s += expf(lg[i] - m);
        const float ls = logf(s) + m;
        for (int i = 0; i < NCLS; ++i) out[(size_t)g * NCLS + i] = lg[i] - ls;
    }
}

// ---------------------------------------------------------------------------
extern "C" void kernel_launch(void* const* d_in, const int* in_sizes, int n_in,
                              void* d_out, int out_size, void* d_ws, size_t ws_size,
                              hipStream_t stream) {
    const float* x_in  = (const float*)d_in[0];
    const int*   ei    = (const int*)d_in[1];
    const int*   batch = (const int*)d_in[2];
    const float* fc_w  = (const float*)d_in[3];
    const float* fc_b  = (const float*)d_in[4];
    const float* mg1_w = (const float*)d_in[5];
    const float* mg1_b = (const float*)d_in[6];
    const float* mg2_w = (const float*)d_in[7];
    const float* mg2_b = (const float*)d_in[8];
    const float* gate_w = (const float*)d_in[9];
    const float* gate_b = (const float*)d_in[10];
    const float* rd_w  = (const float*)d_in[11];
    const float* rd_b  = (const float*)d_in[12];
    const float* gru_wih = (const float*)d_in[13];
    const float* gru_whh = (const float*)d_in[14];
    const float* gru_bih = (const float*)d_in[15];
    const float* gru_bhh = (const float*)d_in[16];
    const float* bn_g  = (const float*)d_in[17];
    const float* bn_b  = (const float*)d_in[18];
    const float* clf1_w = (const float*)d_in[19];
    const float* clf1_b = (const float*)d_in[20];
    const float* clf2_w = (const float*)d_in[21];
    const float* clf2_b = (const float*)d_in[22];

    float* ws = (float*)d_ws;
    size_t off = 0;
    float* cur0 = ws + off; off += (size_t)N * Dk;
    float* cur1 = ws + off; off += (size_t)N * Dk;
    float* xa   = ws + off; off += (size_t)N * Dk;
    float* xb   = ws + off; off += (size_t)N * Dk;
    float* xr   = ws + off; off += (size_t)N * Dk;
    float* gf   = ws + off; off += (size_t)G * Dk;
    float* gfn  = ws + off; off += (size_t)G * Dk;
    float* gfr  = ws + off; off += (size_t)G * Dk;
    float* gfc  = ws + off; off += (size_t)G * Dk;
    float* giB  = ws + off; off += (size_t)G * 768;
    float* ghB  = ws + off; off += (size_t)G * 768;
    float* gnorm = ws + off; off += G;
    float* gcnt  = ws + off; off += G;
    float* xn   = ws + off; off += (size_t)G * Dk;
    float* hcl  = ws + off; off += (size_t)G * HID;
    float* wihT = ws + off; off += (size_t)768 * Dk;
    float* whhT = ws + off; off += (size_t)768 * Dk;
    int* ideg   = (int*)(ws + off); off += N;
    int* icur   = (int*)(ws + off); off += N;
    int* src_s  = (int*)(ws + off); off += E;
    int* dst_s  = (int*)(ws + off); off += E;
    int* gb_s   = (int*)(ws + off); off += E;
    int* eperm  = (int*)(ws + off); off += E;

    float* out_logits = (float*)d_out;
    float* out_lgl = out_logits + (size_t)G * NCLS;
    float* out_ggl = out_lgl + (size_t)E * L;

    hipMemsetAsync(gf, 0, (size_t)G * Dk * 4, stream);
    hipMemsetAsync(gcnt, 0, (size_t)G * 4, stream);
    hipMemsetAsync(ideg, 0, (size_t)N * 4, stream);
    k_cnt<<<(N + 255) / 256, 256, 0, stream>>>(batch, gcnt);
    k_hist<<<(E + 255) / 256, 256, 0, stream>>>(ei, ideg);
    k_scan<<<1, 256, 0, stream>>>(ideg, icur);
    k_scatter<<<(E + 255) / 256, 256, 0, stream>>>(ei, batch, icur, src_s, dst_s, gb_s, eperm);
    k_transpose<<<(768 * Dk + 255) / 256, 256, 0, stream>>>(gru_wih, wihT, 768, Dk);
    k_transpose<<<(768 * Dk + 255) / 256, 256, 0, stream>>>(gru_whh, whhT, 768, Dk);

    k_fc<<<(N + 31) / 32, 256, 0, stream>>>(x_in, fc_w, fc_b, cur0, N);

    float* cur = cur0;
    float* nxt = cur1;
    const int nblk = (N + 31) / 32;

    auto readout = [&](const float* xcur, int ridx) {
        k_gemm<8><<<dim3(G / 8, 1), 256, 0, stream>>>(gf, rd_w + 256 * Dk, Dk, rd_b, gfr, Dk, G);
        hipMemsetAsync(gfn, 0, (size_t)G * Dk * 4, stream);
        hipMemsetAsync(gnorm, 0, (size_t)G * 4, stream);
        k_readout_node<<<N / RNPB, 256, 0, stream>>>(xcur, xr, gfr, batch, gfn, gnorm);
        k_gemm<8><<<dim3(G / 8, 3), 256, 0, stream>>>(gfn, wihT, 768, gru_bih, giB, 768, G);
        k_gemm<8><<<dim3(G / 8, 3), 256, 0, stream>>>(gf, whhT, 768, gru_bhh, ghB, 768, G);
        k_gru_ew<<<G, 256, 0, stream>>>(giB, ghB, gf);
        k_ggl<<<1, 64, 0, stream>>>(gnorm, gcnt, out_ggl + ridx);
    };

    for (int i = 0; i < L; ++i) {
        const float* W1 = mg1_w + (size_t)i * 768 * Dk;
        // xa = cur@W1a, xb = cur@W1b, xr = cur@rd_w  (one A-stage, 3 passes)
        k_mm<3><<<nblk, 128, 0, stream>>>(cur, N, W1, W1 + 256 * Dk, rd_w, xa, xb, xr);
        readout(cur, i);
        k_gemm<8><<<dim3(G / 8, 1), 256, 0, stream>>>(gf, W1 + 512 * Dk, Dk, mg1_b + i * Dk, gfc, Dk, G);
        hipMemsetAsync(nxt, 0, (size_t)N * Dk * 4, stream);
        k_edge_rt<<<E / 32, 128, 0, stream>>>(xa, xb, gfc, src_s, dst_s, gb_s, eperm,
                                              mg2_w + (size_t)i * Dk * Dk, mg2_b + i * Dk,
                                              gate_w + (size_t)i * Dk * Dk, gate_b + i * Dk,
                                              nxt, out_lgl, i);
        float* tmp = cur; cur = nxt; nxt = tmp;
    }
    k_mm<1><<<nblk, 128, 0, stream>>>(cur, N, rd_w, nullptr, nullptr, xr, nullptr, nullptr);
    readout(cur, L);

    k_bn<<<1, 256, 0, stream>>>(gf, bn_g, bn_b, xn);
    k_clf1<<<G, 256, 0, stream>>>(xn, clf1_w, clf1_b, hcl);
    k_clf2<<<G, 256, 0, stream>>>(hcl, clf2_w, clf2_b, out_logits);
}

// Round 8
// 1622.932 us; speedup vs baseline: 1.4840x; 1.4840x over previous
//
#include <hip/hip_runtime.h>
#include <math.h>

// Problem constants (match reference)
constexpr int N = 10000, E = 100000, G = 64;
constexpr int F = 64, Dk = 256, L = 3;
constexpr int HID = 256, NCLS = 10;

typedef __attribute__((ext_vector_type(8))) short short8v;   // 8 bf16 (4 VGPR)
typedef __attribute__((ext_vector_type(4))) float f32x4;

__device__ __forceinline__ float sigmoidf_(float x) {
    return 1.0f / (1.0f + __expf(-x));
}
__device__ __forceinline__ float leakyf_(float v) {
    return v > 0.0f ? v : 0.01f * v;
}

// bf16 round-to-nearest-even, bit-level (avoids hip_bf16 API differences)
__device__ __forceinline__ unsigned short f2bf(float f) {
    unsigned int u = __float_as_uint(f);
    u = (u + 0x7fffu + ((u >> 16) & 1u)) >> 16;
    return (unsigned short)u;
}
__device__ __forceinline__ float bf2f(unsigned short b) {
    return __uint_as_float(((unsigned int)b) << 16);
}
__device__ __forceinline__ void split_bf16(float v, unsigned short& hb, unsigned short& lb) {
    hb = f2bf(v);
    lb = f2bf(v - bf2f(hb));
}

__device__ __forceinline__ f32x4 mfma16(short8v a, short8v b, f32x4 c) {
    return __builtin_amdgcn_mfma_f32_16x16x32_bf16(a, b, c, 0, 0, 0);
}

// ---------------------------------------------------------------------------
// Edge sort by dst: histogram -> single-block scan -> scatter.
// ---------------------------------------------------------------------------
__global__ void k_hist(const int* __restrict__ ei, int* __restrict__ deg) {
    const int e = blockIdx.x * 256 + threadIdx.x;
    if (e < E) atomicAdd(&deg[ei[E + e]], 1);
}

__global__ void k_scan(const int* __restrict__ deg, int* __restrict__ cursor) {
    __shared__ int part[256];
    __shared__ int off[256];
    const int t = threadIdx.x;
    const int base = t * 40;  // 256*40 = 10240 >= N
    int s = 0;
    for (int i = 0; i < 40; ++i) {
        const int idx = base + i;
        if (idx < N) s += deg[idx];
    }
    part[t] = s;
    __syncthreads();
    if (t == 0) {
        int acc = 0;
        for (int i = 0; i < 256; ++i) { off[i] = acc; acc += part[i]; }
    }
    __syncthreads();
    int run = off[t];
    for (int i = 0; i < 40; ++i) {
        const int idx = base + i;
        if (idx < N) { cursor[idx] = run; run += deg[idx]; }
    }
}

__global__ void k_scatter(const int* __restrict__ ei, const int* __restrict__ batch,
                          int* __restrict__ cursor, int* __restrict__ src_s,
                          int* __restrict__ dst_s, int* __restrict__ gb_s,
                          int* __restrict__ eperm) {
    const int e = blockIdx.x * 256 + threadIdx.x;
    if (e < E) {
        const int d = ei[E + e];
        const int pos = atomicAdd(&cursor[d], 1);
        dst_s[pos] = d;
        src_s[pos] = ei[e];
        gb_s[pos] = batch[d];
        eperm[pos] = e;
    }
}

// ---------------------------------------------------------------------------
// Weight pre-pack: 13 matrices 256x256 -> bf16 hi/lo, per-lane MFMA B-frag
// order: out[(((nt*8)+ks)*64 + l)*8 + i] = W[k][c], c = nt*16+(l&15),
// k = ks*32 + (l>>4)*8 + i.  One element per thread.
// mats: 0-2 W2_i, 3-5 Wg_i, 6-8 W1a_i, 9-11 W1b_i, 12 rd_w(first half)
// ---------------------------------------------------------------------------
struct PackSrcs { const float* p[13]; };

__global__ void k_packw(PackSrcs ps, unsigned short* __restrict__ whi,
                        unsigned short* __restrict__ wlo) {
    const int tid = blockIdx.x * 256 + threadIdx.x;   // 13*65536 total
    const int mat = tid >> 16;
    const int f = tid & 65535;
    const int i = f & 7, l = (f >> 3) & 63, ks = (f >> 9) & 7, nt = (f >> 12) & 15;
    const int k = ks * 32 + ((l >> 4) << 3) + i;
    const int c = nt * 16 + (l & 15);
    const float v = ps.p[mat][k * 256 + c];
    unsigned short hb, lb;
    split_bf16(v, hb, lb);
    whi[tid] = hb;
    wlo[tid] = lb;
}

// ---------------------------------------------------------------------------
// MFMA fused edge kernel (edges pre-sorted by dst):
//   h1  = leaky(xa[dst]+xb[src]+gfc[batch[dst]])  (gfc includes b1)
//   msg = leaky(h1 @ W2 + b2) ; gp = msg @ Wg + bg ; lw = sigmoid(gp)*msg
//   lgl[eperm[e]] = ||lw|| ; nxt[dst] += lw*msg (segmented atomics)
// 256 thr = 4 waves in 2x2 quadrants (16 rows x 128 cols each).
// A (h1/msg) split hi/lo bf16 in LDS with XOR frag swizzle; W pre-packed.
// 3-MFMA split product per 16x16x32 tile; msg kept in regs across GEMM2.
// ---------------------------------------------------------------------------
__global__ __launch_bounds__(256, 2) void k_edge_mf(
    const float* __restrict__ xa, const float* __restrict__ xb,
    const float* __restrict__ gfc,
    const int* __restrict__ src_s, const int* __restrict__ dst_s,
    const int* __restrict__ gb_s, const int* __restrict__ eperm,
    const unsigned short* __restrict__ w2h, const unsigned short* __restrict__ w2l,
    const float* __restrict__ b2,
    const unsigned short* __restrict__ wgh, const unsigned short* __restrict__ wgl,
    const float* __restrict__ bg,
    float* __restrict__ nxt, float* __restrict__ lgl, int layer) {
    __shared__ short8v ahv[1024];   // 16 KB  A hi (32 rows x 32 frags)
    __shared__ short8v alv[1024];   // 16 KB  A lo
    __shared__ int sdst[32];
    __shared__ float prow[2][32];

    const int t = threadIdx.x;
    // bijective chunked XCD swizzle
    constexpr int NBLK = E / 32;               // 3125
    constexpr int qq = NBLK / 8, rr = NBLK % 8;
    const int orig = blockIdx.x;
    const int xcd = orig & 7, pos = orig >> 3;
    const int bid = (xcd < rr ? xcd * (qq + 1) : rr * (qq + 1) + (xcd - rr) * qq) + pos;
    const int e0 = bid * 32;

    if (t < 32) sdst[t] = dst_s[e0 + t];

    // ---- h1 build: 8 threads/row, 4x 8-elem chunks each, split to LDS ----
    {
        const int r = t >> 3, l8 = t & 7;
        const int d = dst_s[e0 + r], s = src_s[e0 + r], b = gb_s[e0 + r];
        const float4* pa = (const float4*)(xa + (size_t)d * Dk);
        const float4* pb = (const float4*)(xb + (size_t)s * Dk);
        const float4* pg = (const float4*)(gfc + (size_t)b * Dk);
        const int rsw = r & 7;
#pragma unroll
        for (int j = 0; j < 4; ++j) {
            const int k8 = l8 + 8 * j;          // 8-elem chunk id 0..31
            const int ci = k8 * 2;
            const float4 a0 = pa[ci], a1 = pa[ci + 1];
            const float4 b0 = pb[ci], b1 = pb[ci + 1];
            const float4 g0 = pg[ci], g1 = pg[ci + 1];
            float v[8];
            v[0] = leakyf_(a0.x + b0.x + g0.x); v[1] = leakyf_(a0.y + b0.y + g0.y);
            v[2] = leakyf_(a0.z + b0.z + g0.z); v[3] = leakyf_(a0.w + b0.w + g0.w);
            v[4] = leakyf_(a1.x + b1.x + g1.x); v[5] = leakyf_(a1.y + b1.y + g1.y);
            v[6] = leakyf_(a1.z + b1.z + g1.z); v[7] = leakyf_(a1.w + b1.w + g1.w);
            short8v hv, lv;
#pragma unroll
            for (int ii = 0; ii < 8; ++ii) {
                unsigned short hb, lb;
                split_bf16(v[ii], hb, lb);
                hv[ii] = (short)hb; lv[ii] = (short)lb;
            }
            const int fi = (r * 32 + k8) ^ rsw;
            ahv[fi] = hv; alv[fi] = lv;
        }
    }
    __syncthreads();

    const int l = t & 63, wid = t >> 6;
    const int wr = wid >> 1, wc = wid & 1;
    const int rb = wr * 16, cb = wc * 128;
    const int colbase = cb + (l & 15);          // + nt*16
    const int arow = rb + (l & 15);
    const int art = arow * 32, asw = arow & 7;
    const int akb = l >> 4;
    const int ntg0 = cb >> 4;                    // 0 or 8

    const short8v* W2H = (const short8v*)w2h;
    const short8v* W2L = (const short8v*)w2l;
    const short8v* WGH = (const short8v*)wgh;
    const short8v* WGL = (const short8v*)wgl;

    f32x4 acc[8];
    // ================= GEMM1: msg = leaky(h1 @ W2 + b2) =================
#pragma unroll
    for (int nt = 0; nt < 8; ++nt) {
        const float bb = b2[colbase + nt * 16];
        acc[nt] = f32x4{bb, bb, bb, bb};
    }
#pragma unroll
    for (int ks = 0; ks < 8; ++ks) {
        const int ai = (art + ks * 4 + akb) ^ asw;
        const short8v ah = ahv[ai];
        const short8v al = alv[ai];
        short8v bh[8], bl[8];
#pragma unroll
        for (int nt = 0; nt < 8; ++nt) {
            const int wi = ((ntg0 + nt) * 8 + ks) * 64 + l;
            bh[nt] = W2H[wi]; bl[nt] = W2L[wi];
        }
#pragma unroll
        for (int nt = 0; nt < 8; ++nt) acc[nt] = mfma16(ah, bh[nt], acc[nt]);
#pragma unroll
        for (int nt = 0; nt < 8; ++nt) acc[nt] = mfma16(al, bh[nt], acc[nt]);
#pragma unroll
        for (int nt = 0; nt < 8; ++nt) acc[nt] = mfma16(ah, bl[nt], acc[nt]);
    }
    // msg = leaky(acc) kept in registers
    f32x4 msg[8];
#pragma unroll
    for (int nt = 0; nt < 8; ++nt) {
#pragma unroll
        for (int r = 0; r < 4; ++r) msg[nt][r] = leakyf_(acc[nt][r]);
    }
    __syncthreads();   // all GEMM1 A-reads done before overwrite
    // write msg hi/lo back to LDS in A-layout (swizzled), scalar stores
    {
        unsigned short* AH = (unsigned short*)ahv;
        unsigned short* AL = (unsigned short*)alv;
        const int r0w = rb + (l >> 4) * 4;
#pragma unroll
        for (int r = 0; r < 4; ++r) {
            const int row = r0w + r;
            const int sw = (row & 7) << 3;
#pragma unroll
            for (int nt = 0; nt < 8; ++nt) {
                const int col = colbase + nt * 16;
                unsigned short hb, lb;
                split_bf16(msg[nt][r], hb, lb);
                const int si = (row * 256 + col) ^ sw;
                AH[si] = hb; AL[si] = lb;
            }
        }
    }
    __syncthreads();   // msg tile complete

    // ================= GEMM2: gp = msg @ Wg + bg =================
#pragma unroll
    for (int nt = 0; nt < 8; ++nt) {
        const float bb = bg[colbase + nt * 16];
        acc[nt] = f32x4{bb, bb, bb, bb};
    }
#pragma unroll
    for (int ks = 0; ks < 8; ++ks) {
        const int ai = (art + ks * 4 + akb) ^ asw;
        const short8v ah = ahv[ai];
        const short8v al = alv[ai];
        short8v bh[8], bl[8];
#pragma unroll
        for (int nt = 0; nt < 8; ++nt) {
            const int wi = ((ntg0 + nt) * 8 + ks) * 64 + l;
            bh[nt] = WGH[wi]; bl[nt] = WGL[wi];
        }
#pragma unroll
        for (int nt = 0; nt < 8; ++nt) acc[nt] = mfma16(ah, bh[nt], acc[nt]);
#pragma unroll
        for (int nt = 0; nt < 8; ++nt) acc[nt] = mfma16(al, bh[nt], acc[nt]);
#pragma unroll
        for (int nt = 0; nt < 8; ++nt) acc[nt] = mfma16(ah, bl[nt], acc[nt]);
    }

    // ---- epilogue: lw = sigmoid(gp)*msg; segmented scatter; row norms ----
    {
        float vs[8];
#pragma unroll
        for (int nt = 0; nt < 8; ++nt) vs[nt] = 0.0f;
        const int r0w = rb + (l >> 4) * 4;
#pragma unroll
        for (int r = 0; r < 4; ++r) {
            const int row = r0w + r;
            const int d = sdst[row];
            float sr = 0.0f;
#pragma unroll
            for (int nt = 0; nt < 8; ++nt) {
                const float m = msg[nt][r];
                const float lw = sigmoidf_(acc[nt][r]) * m;
                vs[nt] += lw * m;
                sr += lw * lw;
            }
            const bool flush = (r == 3) || (sdst[row + 1] != d);
            if (flush) {
                float* basep = nxt + (size_t)d * Dk;
#pragma unroll
                for (int nt = 0; nt < 8; ++nt) {
                    atomicAdd(basep + colbase + nt * 16, vs[nt]);
                    vs[nt] = 0.0f;
                }
            }
            sr += __shfl_xor(sr, 1, 64);
            sr += __shfl_xor(sr, 2, 64);
            sr += __shfl_xor(sr, 4, 64);
            sr += __shfl_xor(sr, 8, 64);   // sum over 16-lane col group
            if ((l & 15) == 0) prow[wc][row] = sr;
        }
    }
    __syncthreads();
    if (t < 32)
        lgl[(size_t)eperm[e0 + t] * L + layer] = sqrtf(prow[0][t] + prow[1][t]);
}

// ---------------------------------------------------------------------------
// MFMA node GEMM, NW packed weight streams sharing one A tile:
//   C_w[M,256] = A[M,256] @ W_w   (no bias)
// ---------------------------------------------------------------------------
template <int NW>
__global__ __launch_bounds__(256, 2) void k_mm_mf(
    const float* __restrict__ A, int M,
    const unsigned short* __restrict__ h0, const unsigned short* __restrict__ l0,
    const unsigned short* __restrict__ h1, const unsigned short* __restrict__ l1,
    const unsigned short* __restrict__ h2, const unsigned short* __restrict__ l2,
    float* __restrict__ C0, float* __restrict__ C1, float* __restrict__ C2) {
    __shared__ short8v ahv[1024];
    __shared__ short8v alv[1024];
    const int t = threadIdx.x;
    const int r0 = blockIdx.x * 32;

    {   // stage A rows (clamped for tail), split hi/lo
        const int r = t >> 3, l8 = t & 7;
        int row = r0 + r;
        if (row >= M) row = M - 1;
        const float4* pa = (const float4*)(A + (size_t)row * Dk);
        const int rsw = r & 7;
#pragma unroll
        for (int j = 0; j < 4; ++j) {
            const int k8 = l8 + 8 * j;
            const int ci = k8 * 2;
            const float4 a0 = pa[ci], a1 = pa[ci + 1];
            const float v[8] = {a0.x, a0.y, a0.z, a0.w, a1.x, a1.y, a1.z, a1.w};
            short8v hv, lv;
#pragma unroll
            for (int ii = 0; ii < 8; ++ii) {
                unsigned short hb, lb;
                split_bf16(v[ii], hb, lb);
                hv[ii] = (short)hb; lv[ii] = (short)lb;
            }
            const int fi = (r * 32 + k8) ^ rsw;
            ahv[fi] = hv; alv[fi] = lv;
        }
    }
    __syncthreads();

    const int l = t & 63, wid = t >> 6;
    const int wr = wid >> 1, wc = wid & 1;
    const int rb = wr * 16, cb = wc * 128;
    const int colbase = cb + (l & 15);
    const int arow = rb + (l & 15);
    const int art = arow * 32, asw = arow & 7;
    const int akb = l >> 4;
    const int ntg0 = cb >> 4;

    const unsigned short* hs[3] = {h0, h1, h2};
    const unsigned short* ls[3] = {l0, l1, l2};
    float* Cs[3] = {C0, C1, C2};
#pragma unroll
    for (int w = 0; w < NW; ++w) {
        const short8v* WH = (const short8v*)hs[w];
        const short8v* WL = (const short8v*)ls[w];
        f32x4 acc[8];
#pragma unroll
        for (int nt = 0; nt < 8; ++nt) acc[nt] = f32x4{0.f, 0.f, 0.f, 0.f};
#pragma unroll
        for (int ks = 0; ks < 8; ++ks) {
            const int ai = (art + ks * 4 + akb) ^ asw;
            const short8v ah = ahv[ai];
            const short8v al = alv[ai];
            short8v bh[8], bl[8];
#pragma unroll
            for (int nt = 0; nt < 8; ++nt) {
                const int wi = ((ntg0 + nt) * 8 + ks) * 64 + l;
                bh[nt] = WH[wi]; bl[nt] = WL[wi];
            }
#pragma unroll
            for (int nt = 0; nt < 8; ++nt) acc[nt] = mfma16(ah, bh[nt], acc[nt]);
#pragma unroll
            for (int nt = 0; nt < 8; ++nt) acc[nt] = mfma16(al, bh[nt], acc[nt]);
#pragma unroll
            for (int nt = 0; nt < 8; ++nt) acc[nt] = mfma16(ah, bl[nt], acc[nt]);
        }
        float* Cp = Cs[w];
        const int r0w = rb + (l >> 4) * 4;
#pragma unroll
        for (int r = 0; r < 4; ++r) {
            const int row = r0 + r0w + r;
            if (row < M) {
#pragma unroll
                for (int nt = 0; nt < 8; ++nt)
                    Cp[(size_t)row * Dk + colbase + nt * 16] = acc[nt][r];
            }
        }
    }
}

// ---------------------------------------------------------------------------
// Small GEMM for G-row matrices: C[M,ncols] = A[M,256] @ B (+bias)
// ---------------------------------------------------------------------------
template <int ROWS>
__global__ void k_gemm(const float* __restrict__ A,
                       const float* __restrict__ B, int ldb,
                       const float* __restrict__ bias,
                       float* __restrict__ C, int ldc, int M) {
    __shared__ float Ald[ROWS][Dk];
    const int t = threadIdx.x;
    const int r0 = blockIdx.x * ROWS;
#pragma unroll
    for (int i = 0; i < ROWS; ++i)
        Ald[i][t] = (r0 + i < M) ? A[(size_t)(r0 + i) * Dk + t] : 0.0f;
    __syncthreads();

    const int c = blockIdx.y * 256 + t;
    float acc[ROWS];
    const float bi = bias ? bias[c] : 0.0f;
#pragma unroll
    for (int e = 0; e < ROWS; ++e) acc[e] = bi;

    for (int k = 0; k < Dk; k += 4) {
        const float w0 = B[(size_t)(k + 0) * ldb + c];
        const float w1 = B[(size_t)(k + 1) * ldb + c];
        const float w2 = B[(size_t)(k + 2) * ldb + c];
        const float w3 = B[(size_t)(k + 3) * ldb + c];
#pragma unroll
        for (int e = 0; e < ROWS; ++e) {
            const float4 a = *reinterpret_cast<const float4*>(&Ald[e][k]);
            acc[e] = fmaf(a.x, w0, acc[e]);
            acc[e] = fmaf(a.y, w1, acc[e]);
            acc[e] = fmaf(a.z, w2, acc[e]);
            acc[e] = fmaf(a.w, w3, acc[e]);
        }
    }
#pragma unroll
    for (int e = 0; e < ROWS; ++e)
        if (r0 + e < M) C[(size_t)(r0 + e) * ldc + c] = acc[e];
}

// fc: C[M,256] = A[M,64] @ B[64,256] + bias
__global__ void k_fc(const float* __restrict__ A, const float* __restrict__ B,
                     const float* __restrict__ bias, float* __restrict__ C, int M) {
    __shared__ float Ald[32][F];
    const int t = threadIdx.x;
    const int r0 = blockIdx.x * 32;
    for (int i = t; i < 32 * F; i += 256) {
        int r = i >> 6, k = i & 63;
        Ald[r][k] = (r0 + r < M) ? A[(size_t)(r0 + r) * F + k] : 0.0f;
    }
    __syncthreads();
    const int c = t;
    float acc[32];
    const float bi = bias[c];
#pragma unroll
    for (int e = 0; e < 32; ++e) acc[e] = bi;
    for (int k = 0; k < F; k += 4) {
        const float w0 = B[(size_t)(k + 0) * Dk + c];
        const float w1 = B[(size_t)(k + 1) * Dk + c];
        const float w2 = B[(size_t)(k + 2) * Dk + c];
        const float w3 = B[(size_t)(k + 3) * Dk + c];
#pragma unroll
        for (int e = 0; e < 32; ++e) {
            const float4 a = *reinterpret_cast<const float4*>(&Ald[e][k]);
            acc[e] = fmaf(a.x, w0, acc[e]);
            acc[e] = fmaf(a.y, w1, acc[e]);
            acc[e] = fmaf(a.z, w2, acc[e]);
            acc[e] = fmaf(a.w, w3, acc[e]);
        }
    }
#pragma unroll
    for (int e = 0; e < 32; ++e)
        if (r0 + e < M) C[(size_t)(r0 + e) * Dk + c] = acc[e];
}

// ---------------------------------------------------------------------------
// Readout node pass (batch sorted): run-accumulated scatter.
// ---------------------------------------------------------------------------
constexpr int RNPB = 40;  // nodes per block, 250 blocks
__global__ void k_readout_node(const float* __restrict__ x, const float* __restrict__ xr,
                               const float* __restrict__ gfr, const int* __restrict__ batch,
                               float* __restrict__ gfn, float* __restrict__ gnorm) {
    const int t = threadIdx.x;
    const int n0 = blockIdx.x * RNPB;
    {   // phase A
        const int c = t;
        float acc = 0.0f;
        int bprev = batch[n0];
        for (int i = 0; i < RNPB; ++i) {
            const int n = n0 + i;
            const int b = batch[n];
            if (b != bprev) {
                atomicAdd(&gfn[(size_t)bprev * Dk + c], acc);
                acc = 0.0f;
                bprev = b;
            }
            const float g = sigmoidf_(xr[(size_t)n * Dk + c] + gfr[(size_t)b * Dk + c]);
            acc = fmaf(g, x[(size_t)n * Dk + c], acc);
        }
        atomicAdd(&gfn[(size_t)bprev * Dk + c], acc);
    }
    {   // phase B
        const int lane = t & 63, wv = t >> 6;
        float rs = 0.0f;
        int bprev = -1;
        for (int i = wv; i < RNPB; i += 4) {
            const int n = n0 + i;
            const int b = batch[n];
            const float4 vr = *(const float4*)(xr + (size_t)n * Dk + lane * 4);
            const float4 vg = *(const float4*)(gfr + (size_t)b * Dk + lane * 4);
            const float g0 = sigmoidf_(vr.x + vg.x), g1 = sigmoidf_(vr.y + vg.y);
            const float g2 = sigmoidf_(vr.z + vg.z), g3 = sigmoidf_(vr.w + vg.w);
            float s = g0 * g0 + g1 * g1 + g2 * g2 + g3 * g3;
            s += __shfl_xor(s, 1, 64);
            s += __shfl_xor(s, 2, 64);
            s += __shfl_xor(s, 4, 64);
            s += __shfl_xor(s, 8, 64);
            s += __shfl_xor(s, 16, 64);
            s += __shfl_xor(s, 32, 64);
            if (lane == 0) {
                if (b != bprev && bprev >= 0) {
                    atomicAdd(&gnorm[bprev], rs);
                    rs = 0.0f;
                }
                bprev = b;
                rs += sqrtf(s);
            }
        }
        if (lane == 0 && bprev >= 0) atomicAdd(&gnorm[bprev], rs);
    }
}

__global__ void k_cnt(const int* __restrict__ batch, float* __restrict__ gcnt) {
    const int n = blockIdx.x * 256 + threadIdx.x;
    if (n < N) atomicAdd(&gcnt[batch[n]], 1.0f);
}

__global__ void k_ggl(const float* __restrict__ gnorm, const float* __restrict__ gcnt,
                      float* __restrict__ out) {
    const int t = threadIdx.x;  // 64 threads
    float v = gnorm[t] / fmaxf(gcnt[t], 1.0f);
#pragma unroll
    for (int off = 32; off; off >>= 1) v += __shfl_xor(v, off, 64);
    if (t == 0) *out = v * (1.0f / G);
}

// transpose in[rows,cols] -> out[cols,rows]
__global__ void k_transpose(const float* __restrict__ in, float* __restrict__ out,
                            int rows, int cols) {
    const int idx = blockIdx.x * 256 + threadIdx.x;
    if (idx < rows * cols) {
        const int r = idx / cols, c = idx % cols;
        out[(size_t)c * rows + r] = in[(size_t)r * cols + c];
    }
}

// GRU elementwise combine (gi, gh are [G,768]); gf updated in place.
__global__ void k_gru_ew(const float* __restrict__ gi, const float* __restrict__ gh,
                         float* __restrict__ gf) {
    const int g = blockIdx.x, d = threadIdx.x;
    const float* Gi = gi + (size_t)g * 768;
    const float* Gh = gh + (size_t)g * 768;
    const float h = gf[(size_t)g * Dk + d];
    const float r = sigmoidf_(Gi[d] + Gh[d]);
    const float z = sigmoidf_(Gi[256 + d] + Gh[256 + d]);
    const float nn = tanhf(Gi[512 + d] + r * Gh[512 + d]);
    gf[(size_t)g * Dk + d] = (1.0f - z) * nn + z * h;
}

// BatchNorm (training stats over G graphs) -> xn
__global__ void k_bn(const float* __restrict__ gf, const float* __restrict__ bg,
                     const float* __restrict__ bb, float* __restrict__ xn) {
    const int f = threadIdx.x;
    float mu = 0.0f;
    for (int g = 0; g < G; ++g) mu += gf[(size_t)g * Dk + f];
    mu *= (1.0f / G);
    float var = 0.0f;
    for (int g = 0; g < G; ++g) {
        const float d = gf[(size_t)g * Dk + f] - mu;
        var += d * d;
    }
    var *= (1.0f / G);
    const float inv = (1.0f / sqrtf(var + 1e-5f)) * bg[f];
    const float bet = bb[f];
    for (int g = 0; g < G; ++g)
        xn[(size_t)g * Dk + f] = (gf[(size_t)g * Dk + f] - mu) * inv + bet;
}

__global__ void k_clf1(const float* __restrict__ xn, const float* __restrict__ W,
                       const float* __restrict__ b, float* __restrict__ out) {
    __shared__ float row[Dk];
    const int g = blockIdx.x, t = threadIdx.x;
    row[t] = xn[(size_t)g * Dk + t];
    __syncthreads();
    float acc = b[t];
    for (int k = 0; k < Dk; k += 4) {
        const float4 a = *reinterpret_cast<const float4*>(&row[k]);
        acc = fmaf(a.x, W[(size_t)(k + 0) * HID + t], acc);
        acc = fmaf(a.y, W[(size_t)(k + 1) * HID + t], acc);
        acc = fmaf(a.z, W[(size_t)(k + 2) * HID + t], acc);
        acc = fmaf(a.w, W[(size_t)(k + 3) * HID + t], acc);
    }
    out[(size_t)g * HID + t] = leakyf_(acc);
}

__global__ void k_clf2(const float* __restrict__ h, const float* __restrict__ W,
                       const float* __restrict__ b, float* __restrict__ out) {
    __shared__ float row[HID];
    __shared__ float lg[NCLS];
    const int g = blockIdx.x, t = threadIdx.x;
    row[t] = h[(size_t)g * HID + t];
    __syncthreads();
    if (t < NCLS) {
        float acc = b[t];
        for (int k = 0; k < HID; ++k) acc = fmaf(row[k], W[(size_t)k * NCLS + t], acc);
        lg[t] = acc;
    }
    __syncthreads();
    if (t == 0) {
        float m = lg[0];
        for (int i = 1; i < NCLS; ++i) m = fmaxf(m, lg[i]);
        float s = 0.0f;
        for (int i = 0; i < NCLS; ++i) s += expf(lg[i] - m);
        const float ls = logf(s) + m;
        for (int i = 0; i < NCLS; ++i) out[(size_t)g * NCLS + i] = lg[i] - ls;
    }
}

// ---------------------------------------------------------------------------
extern "C" void kernel_launch(void* const* d_in, const int* in_sizes, int n_in,
                              void* d_out, int out_size, void* d_ws, size_t ws_size,
                              hipStream_t stream) {
    const float* x_in  = (const float*)d_in[0];
    const int*   ei    = (const int*)d_in[1];
    const int*   batch = (const int*)d_in[2];
    const float* fc_w  = (const float*)d_in[3];
    const float* fc_b  = (const float*)d_in[4];
    const float* mg1_w = (const float*)d_in[5];
    const float* mg1_b = (const float*)d_in[6];
    const float* mg2_w = (const float*)d_in[7];
    const float* mg2_b = (const float*)d_in[8];
    const float* gate_w = (const float*)d_in[9];
    const float* gate_b = (const float*)d_in[10];
    const float* rd_w  = (const float*)d_in[11];
    const float* rd_b  = (const float*)d_in[12];
    const float* gru_wih = (const float*)d_in[13];
    const float* gru_whh = (const float*)d_in[14];
    const float* gru_bih = (const float*)d_in[15];
    const float* gru_bhh = (const float*)d_in[16];
    const float* bn_g  = (const float*)d_in[17];
    const float* bn_b  = (const float*)d_in[18];
    const float* clf1_w = (const float*)d_in[19];
    const float* clf1_b = (const float*)d_in[20];
    const float* clf2_w = (const float*)d_in[21];
    const float* clf2_b = (const float*)d_in[22];

    float* ws = (float*)d_ws;
    size_t off = 0;
    float* cur0 = ws + off; off += (size_t)N * Dk;
    float* cur1 = ws + off; off += (size_t)N * Dk;
    float* xa   = ws + off; off += (size_t)N * Dk;
    float* xb   = ws + off; off += (size_t)N * Dk;
    float* xr   = ws + off; off += (size_t)N * Dk;
    float* gf   = ws + off; off += (size_t)G * Dk;
    float* gfn  = ws + off; off += (size_t)G * Dk;
    float* gfr  = ws + off; off += (size_t)G * Dk;
    float* gfc  = ws + off; off += (size_t)G * Dk;
    float* giB  = ws + off; off += (size_t)G * 768;
    float* ghB  = ws + off; off += (size_t)G * 768;
    float* gnorm = ws + off; off += G;
    float* gcnt  = ws + off; off += G;
    float* xn   = ws + off; off += (size_t)G * Dk;
    float* hcl  = ws + off; off += (size_t)G * HID;
    float* wihT = ws + off; off += (size_t)768 * Dk;
    float* whhT = ws + off; off += (size_t)768 * Dk;
    int* ideg   = (int*)(ws + off); off += N;
    int* icur   = (int*)(ws + off); off += N;
    int* src_s  = (int*)(ws + off); off += E;
    int* dst_s  = (int*)(ws + off); off += E;
    int* gb_s   = (int*)(ws + off); off += E;
    int* eperm  = (int*)(ws + off); off += E;
    unsigned short* whi = (unsigned short*)(ws + off); off += (size_t)13 * 65536 / 2;
    unsigned short* wlo = (unsigned short*)(ws + off); off += (size_t)13 * 65536 / 2;

    float* out_logits = (float*)d_out;
    float* out_lgl = out_logits + (size_t)G * NCLS;
    float* out_ggl = out_lgl + (size_t)E * L;

    hipMemsetAsync(gf, 0, (size_t)G * Dk * 4, stream);
    hipMemsetAsync(gcnt, 0, (size_t)G * 4, stream);
    hipMemsetAsync(ideg, 0, (size_t)N * 4, stream);
    k_cnt<<<(N + 255) / 256, 256, 0, stream>>>(batch, gcnt);
    k_hist<<<(E + 255) / 256, 256, 0, stream>>>(ei, ideg);
    k_scan<<<1, 256, 0, stream>>>(ideg, icur);
    k_scatter<<<(E + 255) / 256, 256, 0, stream>>>(ei, batch, icur, src_s, dst_s, gb_s, eperm);
    k_transpose<<<(768 * Dk + 255) / 256, 256, 0, stream>>>(gru_wih, wihT, 768, Dk);
    k_transpose<<<(768 * Dk + 255) / 256, 256, 0, stream>>>(gru_whh, whhT, 768, Dk);

    // pre-pack GEMM weights into bf16 hi/lo fragment order
    {
        PackSrcs ps;
        for (int i = 0; i < L; ++i) {
            ps.p[0 + i] = mg2_w + (size_t)i * 65536;              // W2_i
            ps.p[3 + i] = gate_w + (size_t)i * 65536;             // Wg_i
            ps.p[6 + i] = mg1_w + (size_t)i * 196608;             // W1a_i
            ps.p[9 + i] = mg1_w + (size_t)i * 196608 + 65536;     // W1b_i
        }
        ps.p[12] = rd_w;                                          // rd_w node half
        k_packw<<<13 * 65536 / 256, 256, 0, stream>>>(ps, whi, wlo);
    }

    k_fc<<<(N + 31) / 32, 256, 0, stream>>>(x_in, fc_w, fc_b, cur0, N);

    float* cur = cur0;
    float* nxt = cur1;
    const int nblk = (N + 31) / 32;

    auto readout = [&](const float* xcur, int ridx) {
        k_gemm<8><<<dim3(G / 8, 1), 256, 0, stream>>>(gf, rd_w + 256 * Dk, Dk, rd_b, gfr, Dk, G);
        hipMemsetAsync(gfn, 0, (size_t)G * Dk * 4, stream);
        hipMemsetAsync(gnorm, 0, (size_t)G * 4, stream);
        k_readout_node<<<N / RNPB, 256, 0, stream>>>(xcur, xr, gfr, batch, gfn, gnorm);
        k_gemm<8><<<dim3(G / 8, 3), 256, 0, stream>>>(gfn, wihT, 768, gru_bih, giB, 768, G);
        k_gemm<8><<<dim3(G / 8, 3), 256, 0, stream>>>(gf, whhT, 768, gru_bhh, ghB, 768, G);
        k_gru_ew<<<G, 256, 0, stream>>>(giB, ghB, gf);
        k_ggl<<<1, 64, 0, stream>>>(gnorm, gcnt, out_ggl + ridx);
    };

    for (int i = 0; i < L; ++i) {
        // xa = cur@W1a, xb = cur@W1b, xr = cur@rd_w  (MFMA, one A-stage)
        k_mm_mf<3><<<nblk, 256, 0, stream>>>(
            cur, N,
            whi + (size_t)(6 + i) * 65536, wlo + (size_t)(6 + i) * 65536,
            whi + (size_t)(9 + i) * 65536, wlo + (size_t)(9 + i) * 65536,
            whi + (size_t)12 * 65536, wlo + (size_t)12 * 65536,
            xa, xb, xr);
        readout(cur, i);
        k_gemm<8><<<dim3(G / 8, 1), 256, 0, stream>>>(gf, mg1_w + (size_t)i * 196608 + 131072,
                                                      Dk, mg1_b + i * Dk, gfc, Dk, G);
        hipMemsetAsync(nxt, 0, (size_t)N * Dk * 4, stream);
        k_edge_mf<<<E / 32, 256, 0, stream>>>(
            xa, xb, gfc, src_s, dst_s, gb_s, eperm,
            whi + (size_t)i * 65536, wlo + (size_t)i * 65536, mg2_b + i * Dk,
            whi + (size_t)(3 + i) * 65536, wlo + (size_t)(3 + i) * 65536, gate_b + i * Dk,
            nxt, out_lgl, i);
        float* tmp = cur; cur = nxt; nxt = tmp;
    }
    k_mm_mf<1><<<nblk, 256, 0, stream>>>(
        cur, N,
        whi + (size_t)12 * 65536, wlo + (size_t)12 * 65536,
        nullptr, nullptr, nullptr, nullptr,
        xr, nullptr, nullptr);
    readout(cur, L);

    k_bn<<<1, 256, 0, stream>>>(gf, bn_g, bn_b, xn);
    k_clf1<<<G, 256, 0, stream>>>(xn, clf1_w, clf1_b, hcl);
    k_clf2<<<G, 256, 0, stream>>>(hcl, clf2_w, clf2_b, out_logits);
}

// Round 9
// 1607.675 us; speedup vs baseline: 1.4981x; 1.0095x over previous
//
#include <hip/hip_runtime.h>
#include <math.h>

// Problem constants (match reference)
constexpr int N = 10000, E = 100000, G = 64;
constexpr int F = 64, Dk = 256, L = 3;
constexpr int HID = 256, NCLS = 10;

typedef __attribute__((ext_vector_type(8))) short short8v;   // 8 bf16 (4 VGPR)
typedef __attribute__((ext_vector_type(4))) float f32x4;

__device__ __forceinline__ float sigmoidf_(float x) {
    return 1.0f / (1.0f + __expf(-x));
}
__device__ __forceinline__ float leakyf_(float v) {
    return v > 0.0f ? v : 0.01f * v;
}

// bf16 round-to-nearest-even, bit-level
__device__ __forceinline__ unsigned short f2bf(float f) {
    unsigned int u = __float_as_uint(f);
    u = (u + 0x7fffu + ((u >> 16) & 1u)) >> 16;
    return (unsigned short)u;
}
__device__ __forceinline__ float bf2f(unsigned short b) {
    return __uint_as_float(((unsigned int)b) << 16);
}
__device__ __forceinline__ void split_bf16(float v, unsigned short& hb, unsigned short& lb) {
    hb = f2bf(v);
    lb = f2bf(v - bf2f(hb));
}

__device__ __forceinline__ f32x4 mfma16(short8v a, short8v b, f32x4 c) {
    return __builtin_amdgcn_mfma_f32_16x16x32_bf16(a, b, c, 0, 0, 0);
}

// ---------------------------------------------------------------------------
// Edge sort by dst: histogram -> single-block scan -> scatter.
// ---------------------------------------------------------------------------
__global__ void k_hist(const int* __restrict__ ei, int* __restrict__ deg) {
    const int e = blockIdx.x * 256 + threadIdx.x;
    if (e < E) atomicAdd(&deg[ei[E + e]], 1);
}

__global__ void k_scan(const int* __restrict__ deg, int* __restrict__ cursor) {
    __shared__ int part[256];
    __shared__ int off[256];
    const int t = threadIdx.x;
    const int base = t * 40;  // 256*40 = 10240 >= N
    int s = 0;
    for (int i = 0; i < 40; ++i) {
        const int idx = base + i;
        if (idx < N) s += deg[idx];
    }
    part[t] = s;
    __syncthreads();
    if (t == 0) {
        int acc = 0;
        for (int i = 0; i < 256; ++i) { off[i] = acc; acc += part[i]; }
    }
    __syncthreads();
    int run = off[t];
    for (int i = 0; i < 40; ++i) {
        const int idx = base + i;
        if (idx < N) { cursor[idx] = run; run += deg[idx]; }
    }
}

__global__ void k_scatter(const int* __restrict__ ei, const int* __restrict__ batch,
                          int* __restrict__ cursor, int* __restrict__ src_s,
                          int* __restrict__ dst_s, int* __restrict__ gb_s,
                          int* __restrict__ eperm) {
    const int e = blockIdx.x * 256 + threadIdx.x;
    if (e < E) {
        const int d = ei[E + e];
        const int pos = atomicAdd(&cursor[d], 1);
        dst_s[pos] = d;
        src_s[pos] = ei[e];
        gb_s[pos] = batch[d];
        eperm[pos] = e;
    }
}

// ---------------------------------------------------------------------------
// Weight pre-pack: 13 matrices 256x256 -> bf16 hi/lo, per-lane MFMA B-frag
// order: out[(((nt*8)+ks)*64 + l)*8 + i] = W[k][c], c = nt*16+(l&15),
// k = ks*32 + (l>>4)*8 + i.
// mats: 0-2 W2_i, 3-5 Wg_i, 6-8 W1a_i, 9-11 W1b_i, 12 rd_w(first half)
// ---------------------------------------------------------------------------
struct PackSrcs { const float* p[13]; };

__global__ void k_packw(PackSrcs ps, unsigned short* __restrict__ whi,
                        unsigned short* __restrict__ wlo) {
    const int tid = blockIdx.x * 256 + threadIdx.x;   // 13*65536 total
    const int mat = tid >> 16;
    const int f = tid & 65535;
    const int i = f & 7, l = (f >> 3) & 63, ks = (f >> 9) & 7, nt = (f >> 12) & 15;
    const int k = ks * 32 + ((l >> 4) << 3) + i;
    const int c = nt * 16 + (l & 15);
    const float v = ps.p[mat][k * 256 + c];
    unsigned short hb, lb;
    split_bf16(v, hb, lb);
    whi[tid] = hb;
    wlo[tid] = lb;
}

// ---------------------------------------------------------------------------
// MFMA fused edge kernel, 64 edges/block (edges pre-sorted by dst):
//   h1  = leaky(xa[dst]+xb[src]+gfc[batch[dst]])  (gfc includes b1)
//   msg = leaky(h1 @ W2 + b2) ; gp = msg @ Wg + bg ; lw = sigmoid(gp)*msg
//   lgl[eperm[e]] = ||lw|| ; nxt[dst] += lw*msg (segmented atomics)
// 256 thr = 4 waves in 2x2 quadrants; wave tile 32 rows x 128 cols
// (2 m-frags x 8 n-frags per thread). A hi/lo bf16 in LDS (64 KB), XOR
// frag swizzle; W pre-packed; B-frag loads chunked by 4 to cap VGPRs.
// 2x arithmetic intensity on the L2 W-stream vs the 32-edge version.
// ---------------------------------------------------------------------------
constexpr int NEBLK = (E + 63) / 64;   // 1563 (tail block half-valid)

__global__ __launch_bounds__(256, 2) void k_edge_mf(
    const float* __restrict__ xa, const float* __restrict__ xb,
    const float* __restrict__ gfc,
    const int* __restrict__ src_s, const int* __restrict__ dst_s,
    const int* __restrict__ gb_s, const int* __restrict__ eperm,
    const unsigned short* __restrict__ w2h, const unsigned short* __restrict__ w2l,
    const float* __restrict__ b2,
    const unsigned short* __restrict__ wgh, const unsigned short* __restrict__ wgl,
    const float* __restrict__ bg,
    float* __restrict__ nxt, float* __restrict__ lgl, int layer) {
    __shared__ short8v ahv[2048];   // 32 KB  A hi (64 rows x 32 frags)
    __shared__ short8v alv[2048];   // 32 KB  A lo
    __shared__ int sdst[64];
    __shared__ float prow[2][64];

    const int t = threadIdx.x;
    // bijective chunked XCD swizzle
    constexpr int qq = NEBLK / 8, rr = NEBLK % 8;
    const int orig = blockIdx.x;
    const int xcd = orig & 7, pos = orig >> 3;
    const int bid = (xcd < rr ? xcd * (qq + 1) : rr * (qq + 1) + (xcd - rr) * qq) + pos;
    const int e0 = bid * 64;

    if (t < 64) sdst[t] = dst_s[e0 + t];

    // ---- h1 build: 4 threads/row, 8x 8-elem chunks each, split to LDS ----
    {
        const int r = t >> 2, l4 = t & 3;
        const int d = dst_s[e0 + r], s = src_s[e0 + r], b = gb_s[e0 + r];
        const float4* pa = (const float4*)(xa + (size_t)d * Dk);
        const float4* pb = (const float4*)(xb + (size_t)s * Dk);
        const float4* pg = (const float4*)(gfc + (size_t)b * Dk);
        const int rsw = r & 7;
#pragma unroll
        for (int j = 0; j < 8; ++j) {
            const int k8 = l4 + 4 * j;          // chunk id 0..31
            const int ci = k8 * 2;
            const float4 a0 = pa[ci], a1 = pa[ci + 1];
            const float4 b0 = pb[ci], b1 = pb[ci + 1];
            const float4 g0 = pg[ci], g1 = pg[ci + 1];
            float v[8];
            v[0] = leakyf_(a0.x + b0.x + g0.x); v[1] = leakyf_(a0.y + b0.y + g0.y);
            v[2] = leakyf_(a0.z + b0.z + g0.z); v[3] = leakyf_(a0.w + b0.w + g0.w);
            v[4] = leakyf_(a1.x + b1.x + g1.x); v[5] = leakyf_(a1.y + b1.y + g1.y);
            v[6] = leakyf_(a1.z + b1.z + g1.z); v[7] = leakyf_(a1.w + b1.w + g1.w);
            short8v hv, lv;
#pragma unroll
            for (int ii = 0; ii < 8; ++ii) {
                unsigned short hb, lb;
                split_bf16(v[ii], hb, lb);
                hv[ii] = (short)hb; lv[ii] = (short)lb;
            }
            const int fi = (r * 32 + k8) ^ rsw;
            ahv[fi] = hv; alv[fi] = lv;
        }
    }
    __syncthreads();

    const int l = t & 63, wid = t >> 6;
    const int wr = wid >> 1, wc = wid & 1;
    const int rb = wr * 32, cb = wc * 128;
    const int colbase = cb + (l & 15);          // + nt*16
    const int akb = l >> 4;
    const int asw = l & 7;                      // (arow & 7) for both m-frags
    const int ntg0 = cb >> 4;                   // 0 or 8
    const int arow0 = rb + (l & 15);            // m-frag 0 row

    const short8v* W2H = (const short8v*)w2h;
    const short8v* W2L = (const short8v*)w2l;
    const short8v* WGH = (const short8v*)wgh;
    const short8v* WGL = (const short8v*)wgl;

    f32x4 acc[2][8];
    // ================= GEMM1: msg = leaky(h1 @ W2 + b2) =================
#pragma unroll
    for (int mf = 0; mf < 2; ++mf)
#pragma unroll
        for (int nt = 0; nt < 8; ++nt) {
            const float bb = b2[colbase + nt * 16];
            acc[mf][nt] = f32x4{bb, bb, bb, bb};
        }
#pragma unroll
    for (int ks = 0; ks < 8; ++ks) {
        short8v ah[2], al[2];
#pragma unroll
        for (int mf = 0; mf < 2; ++mf) {
            const int ai = ((arow0 + mf * 16) * 32 + ks * 4 + akb) ^ asw;
            ah[mf] = ahv[ai]; al[mf] = alv[ai];
        }
#pragma unroll
        for (int ntc = 0; ntc < 2; ++ntc) {
            short8v bh[4], bl[4];
#pragma unroll
            for (int q = 0; q < 4; ++q) {
                const int wi = ((ntg0 + ntc * 4 + q) * 8 + ks) * 64 + l;
                bh[q] = W2H[wi]; bl[q] = W2L[wi];
            }
#pragma unroll
            for (int q = 0; q < 4; ++q)
#pragma unroll
                for (int mf = 0; mf < 2; ++mf) {
                    const int nt = ntc * 4 + q;
                    acc[mf][nt] = mfma16(ah[mf], bh[q], acc[mf][nt]);
                    acc[mf][nt] = mfma16(al[mf], bh[q], acc[mf][nt]);
                    acc[mf][nt] = mfma16(ah[mf], bl[q], acc[mf][nt]);
                }
        }
    }
    // msg = leaky(acc) kept in registers
    f32x4 msg[2][8];
#pragma unroll
    for (int mf = 0; mf < 2; ++mf)
#pragma unroll
        for (int nt = 0; nt < 8; ++nt)
#pragma unroll
            for (int r = 0; r < 4; ++r) msg[mf][nt][r] = leakyf_(acc[mf][nt][r]);
    __syncthreads();   // all GEMM1 A-reads done before overwrite
    // write msg hi/lo back to LDS in A-layout (swizzled), scalar stores
    {
        unsigned short* AH = (unsigned short*)ahv;
        unsigned short* AL = (unsigned short*)alv;
#pragma unroll
        for (int mf = 0; mf < 2; ++mf) {
            const int r0w = rb + mf * 16 + akb * 4;
#pragma unroll
            for (int r = 0; r < 4; ++r) {
                const int row = r0w + r;
                const int sw = (row & 7) << 3;
#pragma unroll
                for (int nt = 0; nt < 8; ++nt) {
                    unsigned short hb, lb;
                    split_bf16(msg[mf][nt][r], hb, lb);
                    const int si = (row * 256 + colbase + nt * 16) ^ sw;
                    AH[si] = hb; AL[si] = lb;
                }
            }
        }
    }
    __syncthreads();   // msg tile complete

    // ================= GEMM2: gp = msg @ Wg + bg =================
#pragma unroll
    for (int mf = 0; mf < 2; ++mf)
#pragma unroll
        for (int nt = 0; nt < 8; ++nt) {
            const float bb = bg[colbase + nt * 16];
            acc[mf][nt] = f32x4{bb, bb, bb, bb};
        }
#pragma unroll
    for (int ks = 0; ks < 8; ++ks) {
        short8v ah[2], al[2];
#pragma unroll
        for (int mf = 0; mf < 2; ++mf) {
            const int ai = ((arow0 + mf * 16) * 32 + ks * 4 + akb) ^ asw;
            ah[mf] = ahv[ai]; al[mf] = alv[ai];
        }
#pragma unroll
        for (int ntc = 0; ntc < 2; ++ntc) {
            short8v bh[4], bl[4];
#pragma unroll
            for (int q = 0; q < 4; ++q) {
                const int wi = ((ntg0 + ntc * 4 + q) * 8 + ks) * 64 + l;
                bh[q] = WGH[wi]; bl[q] = WGL[wi];
            }
#pragma unroll
            for (int q = 0; q < 4; ++q)
#pragma unroll
                for (int mf = 0; mf < 2; ++mf) {
                    const int nt = ntc * 4 + q;
                    acc[mf][nt] = mfma16(ah[mf], bh[q], acc[mf][nt]);
                    acc[mf][nt] = mfma16(al[mf], bh[q], acc[mf][nt]);
                    acc[mf][nt] = mfma16(ah[mf], bl[q], acc[mf][nt]);
                }
        }
    }

    // ---- epilogue: lw = sigmoid(gp)*msg; segmented scatter; row norms ----
#pragma unroll
    for (int mf = 0; mf < 2; ++mf) {
        float vs[8];
#pragma unroll
        for (int nt = 0; nt < 8; ++nt) vs[nt] = 0.0f;
        const int r0w = rb + mf * 16 + akb * 4;
#pragma unroll
        for (int r = 0; r < 4; ++r) {
            const int row = r0w + r;
            const int d = sdst[row];
            float sr = 0.0f;
#pragma unroll
            for (int nt = 0; nt < 8; ++nt) {
                const float m = msg[mf][nt][r];
                const float lw = sigmoidf_(acc[mf][nt][r]) * m;
                vs[nt] += lw * m;
                sr += lw * lw;
            }
            const bool flush = (r == 3) || (sdst[row + 1] != d);
            if (flush) {
                if (e0 + row < E) {
                    float* basep = nxt + (size_t)d * Dk;
#pragma unroll
                    for (int nt = 0; nt < 8; ++nt)
                        atomicAdd(basep + colbase + nt * 16, vs[nt]);
                }
#pragma unroll
                for (int nt = 0; nt < 8; ++nt) vs[nt] = 0.0f;
            }
            sr += __shfl_xor(sr, 1, 64);
            sr += __shfl_xor(sr, 2, 64);
            sr += __shfl_xor(sr, 4, 64);
            sr += __shfl_xor(sr, 8, 64);   // sum over 16-lane col group
            if ((l & 15) == 0) prow[wc][row] = sr;
        }
    }
    __syncthreads();
    if (t < 64 && e0 + t < E)
        lgl[(size_t)eperm[e0 + t] * L + layer] = sqrtf(prow[0][t] + prow[1][t]);
}

// ---------------------------------------------------------------------------
// MFMA node GEMM, 64 rows/block, NW packed weight streams sharing one A tile:
//   C_w[M,256] = A[M,256] @ W_w   (no bias)
// ---------------------------------------------------------------------------
template <int NW>
__global__ __launch_bounds__(256, 2) void k_mm_mf(
    const float* __restrict__ A, int M,
    const unsigned short* __restrict__ h0, const unsigned short* __restrict__ l0,
    const unsigned short* __restrict__ h1, const unsigned short* __restrict__ l1,
    const unsigned short* __restrict__ h2, const unsigned short* __restrict__ l2,
    float* __restrict__ C0, float* __restrict__ C1, float* __restrict__ C2) {
    __shared__ short8v ahv[2048];
    __shared__ short8v alv[2048];
    const int t = threadIdx.x;
    const int r0 = blockIdx.x * 64;

    {   // stage A rows (clamped for tail), split hi/lo
        const int r = t >> 2, l4 = t & 3;
        int row = r0 + r;
        if (row >= M) row = M - 1;
        const float4* pa = (const float4*)(A + (size_t)row * Dk);
        const int rsw = r & 7;
#pragma unroll
        for (int j = 0; j < 8; ++j) {
            const int k8 = l4 + 4 * j;
            const int ci = k8 * 2;
            const float4 a0 = pa[ci], a1 = pa[ci + 1];
            const float v[8] = {a0.x, a0.y, a0.z, a0.w, a1.x, a1.y, a1.z, a1.w};
            short8v hv, lv;
#pragma unroll
            for (int ii = 0; ii < 8; ++ii) {
                unsigned short hb, lb;
                split_bf16(v[ii], hb, lb);
                hv[ii] = (short)hb; lv[ii] = (short)lb;
            }
            const int fi = (r * 32 + k8) ^ rsw;
            ahv[fi] = hv; alv[fi] = lv;
        }
    }
    __syncthreads();

    const int l = t & 63, wid = t >> 6;
    const int wr = wid >> 1, wc = wid & 1;
    const int rb = wr * 32, cb = wc * 128;
    const int colbase = cb + (l & 15);
    const int akb = l >> 4;
    const int asw = l & 7;
    const int ntg0 = cb >> 4;
    const int arow0 = rb + (l & 15);

    const unsigned short* hs[3] = {h0, h1, h2};
    const unsigned short* ls[3] = {l0, l1, l2};
    float* Cs[3] = {C0, C1, C2};
#pragma unroll
    for (int w = 0; w < NW; ++w) {
        const short8v* WH = (const short8v*)hs[w];
        const short8v* WL = (const short8v*)ls[w];
        f32x4 acc[2][8];
#pragma unroll
        for (int mf = 0; mf < 2; ++mf)
#pragma unroll
            for (int nt = 0; nt < 8; ++nt) acc[mf][nt] = f32x4{0.f, 0.f, 0.f, 0.f};
#pragma unroll
        for (int ks = 0; ks < 8; ++ks) {
            short8v ah[2], al[2];
#pragma unroll
            for (int mf = 0; mf < 2; ++mf) {
                const int ai = ((arow0 + mf * 16) * 32 + ks * 4 + akb) ^ asw;
                ah[mf] = ahv[ai]; al[mf] = alv[ai];
            }
#pragma unroll
            for (int ntc = 0; ntc < 2; ++ntc) {
                short8v bh[4], bl[4];
#pragma unroll
                for (int q = 0; q < 4; ++q) {
                    const int wi = ((ntg0 + ntc * 4 + q) * 8 + ks) * 64 + l;
                    bh[q] = WH[wi]; bl[q] = WL[wi];
                }
#pragma unroll
                for (int q = 0; q < 4; ++q)
#pragma unroll
                    for (int mf = 0; mf < 2; ++mf) {
                        const int nt = ntc * 4 + q;
                        acc[mf][nt] = mfma16(ah[mf], bh[q], acc[mf][nt]);
                        acc[mf][nt] = mfma16(al[mf], bh[q], acc[mf][nt]);
                        acc[mf][nt] = mfma16(ah[mf], bl[q], acc[mf][nt]);
                    }
            }
        }
        float* Cp = Cs[w];
#pragma unroll
        for (int mf = 0; mf < 2; ++mf) {
            const int r0w = rb + mf * 16 + akb * 4;
#pragma unroll
            for (int r = 0; r < 4; ++r) {
                const int row = r0 + r0w + r;
                if (row < M) {
#pragma unroll
                    for (int nt = 0; nt < 8; ++nt)
                        Cp[(size_t)row * Dk + colbase + nt * 16] = acc[mf][nt][r];
                }
            }
        }
    }
}

// ---------------------------------------------------------------------------
// Small GEMM for G-row matrices: C[M,ncols] = A[M,256] @ B (+bias)
// ---------------------------------------------------------------------------
template <int ROWS>
__global__ void k_gemm(const float* __restrict__ A,
                       const float* __restrict__ B, int ldb,
                       const float* __restrict__ bias,
                       float* __restrict__ C, int ldc, int M) {
    __shared__ float Ald[ROWS][Dk];
    const int t = threadIdx.x;
    const int r0 = blockIdx.x * ROWS;
#pragma unroll
    for (int i = 0; i < ROWS; ++i)
        Ald[i][t] = (r0 + i < M) ? A[(size_t)(r0 + i) * Dk + t] : 0.0f;
    __syncthreads();

    const int c = blockIdx.y * 256 + t;
    float acc[ROWS];
    const float bi = bias ? bias[c] : 0.0f;
#pragma unroll
    for (int e = 0; e < ROWS; ++e) acc[e] = bi;

    for (int k = 0; k < Dk; k += 4) {
        const float w0 = B[(size_t)(k + 0) * ldb + c];
        const float w1 = B[(size_t)(k + 1) * ldb + c];
        const float w2 = B[(size_t)(k + 2) * ldb + c];
        const float w3 = B[(size_t)(k + 3) * ldb + c];
#pragma unroll
        for (int e = 0; e < ROWS; ++e) {
            const float4 a = *reinterpret_cast<const float4*>(&Ald[e][k]);
            acc[e] = fmaf(a.x, w0, acc[e]);
            acc[e] = fmaf(a.y, w1, acc[e]);
            acc[e] = fmaf(a.z, w2, acc[e]);
            acc[e] = fmaf(a.w, w3, acc[e]);
        }
    }
#pragma unroll
    for (int e = 0; e < ROWS; ++e)
        if (r0 + e < M) C[(size_t)(r0 + e) * ldc + c] = acc[e];
}

// fc: C[M,256] = A[M,64] @ B[64,256] + bias
__global__ void k_fc(const float* __restrict__ A, const float* __restrict__ B,
                     const float* __restrict__ bias, float* __restrict__ C, int M) {
    __shared__ float Ald[32][F];
    const int t = threadIdx.x;
    const int r0 = blockIdx.x * 32;
    for (int i = t; i < 32 * F; i += 256) {
        int r = i >> 6, k = i & 63;
        Ald[r][k] = (r0 + r < M) ? A[(size_t)(r0 + r) * F + k] : 0.0f;
    }
    __syncthreads();
    const int c = t;
    float acc[32];
    const float bi = bias[c];
#pragma unroll
    for (int e = 0; e < 32; ++e) acc[e] = bi;
    for (int k = 0; k < F; k += 4) {
        const float w0 = B[(size_t)(k + 0) * Dk + c];
        const float w1 = B[(size_t)(k + 1) * Dk + c];
        const float w2 = B[(size_t)(k + 2) * Dk + c];
        const float w3 = B[(size_t)(k + 3) * Dk + c];
#pragma unroll
        for (int e = 0; e < 32; ++e) {
            const float4 a = *reinterpret_cast<const float4*>(&Ald[e][k]);
            acc[e] = fmaf(a.x, w0, acc[e]);
            acc[e] = fmaf(a.y, w1, acc[e]);
            acc[e] = fmaf(a.z, w2, acc[e]);
            acc[e] = fmaf(a.w, w3, acc[e]);
        }
    }
#pragma unroll
    for (int e = 0; e < 32; ++e)
        if (r0 + e < M) C[(size_t)(r0 + e) * Dk + c] = acc[e];
}

// ---------------------------------------------------------------------------
// Readout node pass (batch sorted): run-accumulated scatter.
// ---------------------------------------------------------------------------
constexpr int RNPB = 40;  // nodes per block, 250 blocks
__global__ void k_readout_node(const float* __restrict__ x, const float* __restrict__ xr,
                               const float* __restrict__ gfr, const int* __restrict__ batch,
                               float* __restrict__ gfn, float* __restrict__ gnorm) {
    const int t = threadIdx.x;
    const int n0 = blockIdx.x * RNPB;
    {   // phase A
        const int c = t;
        float acc = 0.0f;
        int bprev = batch[n0];
        for (int i = 0; i < RNPB; ++i) {
            const int n = n0 + i;
            const int b = batch[n];
            if (b != bprev) {
                atomicAdd(&gfn[(size_t)bprev * Dk + c], acc);
                acc = 0.0f;
                bprev = b;
            }
            const float g = sigmoidf_(xr[(size_t)n * Dk + c] + gfr[(size_t)b * Dk + c]);
            acc = fmaf(g, x[(size_t)n * Dk + c], acc);
        }
        atomicAdd(&gfn[(size_t)bprev * Dk + c], acc);
    }
    {   // phase B
        const int lane = t & 63, wv = t >> 6;
        float rs = 0.0f;
        int bprev = -1;
        for (int i = wv; i < RNPB; i += 4) {
            const int n = n0 + i;
            const int b = batch[n];
            const float4 vr = *(const float4*)(xr + (size_t)n * Dk + lane * 4);
            const float4 vg = *(const float4*)(gfr + (size_t)b * Dk + lane * 4);
            const float g0 = sigmoidf_(vr.x + vg.x), g1 = sigmoidf_(vr.y + vg.y);
            const float g2 = sigmoidf_(vr.z + vg.z), g3 = sigmoidf_(vr.w + vg.w);
            float s = g0 * g0 + g1 * g1 + g2 * g2 + g3 * g3;
            s += __shfl_xor(s, 1, 64);
            s += __shfl_xor(s, 2, 64);
            s += __shfl_xor(s, 4, 64);
            s += __shfl_xor(s, 8, 64);
            s += __shfl_xor(s, 16, 64);
            s += __shfl_xor(s, 32, 64);
            if (lane == 0) {
                if (b != bprev && bprev >= 0) {
                    atomicAdd(&gnorm[bprev], rs);
                    rs = 0.0f;
                }
                bprev = b;
                rs += sqrtf(s);
            }
        }
        if (lane == 0 && bprev >= 0) atomicAdd(&gnorm[bprev], rs);
    }
}

__global__ void k_cnt(const int* __restrict__ batch, float* __restrict__ gcnt) {
    const int n = blockIdx.x * 256 + threadIdx.x;
    if (n < N) atomicAdd(&gcnt[batch[n]], 1.0f);
}

__global__ void k_ggl(const float* __restrict__ gnorm, const float* __restrict__ gcnt,
                      float* __restrict__ out) {
    const int t = threadIdx.x;  // 64 threads
    float v = gnorm[t] / fmaxf(gcnt[t], 1.0f);
#pragma unroll
    for (int off = 32; off; off >>= 1) v += __shfl_xor(v, off, 64);
    if (t == 0) *out = v * (1.0f / G);
}

// transpose in[rows,cols] -> out[cols,rows]
__global__ void k_transpose(const float* __restrict__ in, float* __restrict__ out,
                            int rows, int cols) {
    const int idx = blockIdx.x * 256 + threadIdx.x;
    if (idx < rows * cols) {
        const int r = idx / cols, c = idx % cols;
        out[(size_t)c * rows + r] = in[(size_t)r * cols + c];
    }
}

// GRU elementwise combine (gi, gh are [G,768]); gf updated in place.
__global__ void k_gru_ew(const float* __restrict__ gi, const float* __restrict__ gh,
                         float* __restrict__ gf) {
    const int g = blockIdx.x, d = threadIdx.x;
    const float* Gi = gi + (size_t)g * 768;
    const float* Gh = gh + (size_t)g * 768;
    const float h = gf[(size_t)g * Dk + d];
    const float r = sigmoidf_(Gi[d] + Gh[d]);
    const float z = sigmoidf_(Gi[256 + d] + Gh[256 + d]);
    const float nn = tanhf(Gi[512 + d] + r * Gh[512 + d]);
    gf[(size_t)g * Dk + d] = (1.0f - z) * nn + z * h;
}

// BatchNorm (training stats over G graphs) -> xn
__global__ void k_bn(const float* __restrict__ gf, const float* __restrict__ bg,
                     const float* __restrict__ bb, float* __restrict__ xn) {
    const int f = threadIdx.x;
    float mu = 0.0f;
    for (int g = 0; g < G; ++g) mu += gf[(size_t)g * Dk + f];
    mu *= (1.0f / G);
    float var = 0.0f;
    for (int g = 0; g < G; ++g) {
        const float d = gf[(size_t)g * Dk + f] - mu;
        var += d * d;
    }
    var *= (1.0f / G);
    const float inv = (1.0f / sqrtf(var + 1e-5f)) * bg[f];
    const float bet = bb[f];
    for (int g = 0; g < G; ++g)
        xn[(size_t)g * Dk + f] = (gf[(size_t)g * Dk + f] - mu) * inv + bet;
}

__global__ void k_clf1(const float* __restrict__ xn, const float* __restrict__ W,
                       const float* __restrict__ b, float* __restrict__ out) {
    __shared__ float row[Dk];
    const int g = blockIdx.x, t = threadIdx.x;
    row[t] = xn[(size_t)g * Dk + t];
    __syncthreads();
    float acc = b[t];
    for (int k = 0; k < Dk; k += 4) {
        const float4 a = *reinterpret_cast<const float4*>(&row[k]);
        acc = fmaf(a.x, W[(size_t)(k + 0) * HID + t], acc);
        acc = fmaf(a.y, W[(size_t)(k + 1) * HID + t], acc);
        acc = fmaf(a.z, W[(size_t)(k + 2) * HID + t], acc);
        acc = fmaf(a.w, W[(size_t)(k + 3) * HID + t], acc);
    }
    out[(size_t)g * HID + t] = leakyf_(acc);
}

__global__ void k_clf2(const float* __restrict__ h, const float* __restrict__ W,
                       const float* __restrict__ b, float* __restrict__ out) {
    __shared__ float row[HID];
    __shared__ float lg[NCLS];
    const int g = blockIdx.x, t = threadIdx.x;
    row[t] = h[(size_t)g * HID + t];
    __syncthreads();
    if (t < NCLS) {
        float acc = b[t];
        for (int k = 0; k < HID; ++k) acc = fmaf(row[k], W[(size_t)k * NCLS + t], acc);
        lg[t] = acc;
    }
    __syncthreads();
    if (t == 0) {
        float m = lg[0];
        for (int i = 1; i < NCLS; ++i) m = fmaxf(m, lg[i]);
        float s = 0.0f;
        for (int i = 0; i < NCLS; ++i) s += expf(lg[i] - m);
        const float ls = logf(s) + m;
        for (int i = 0; i < NCLS; ++i) out[(size_t)g * NCLS + i] = lg[i] - ls;
    }
}

// ---------------------------------------------------------------------------
extern "C" void kernel_launch(void* const* d_in, const int* in_sizes, int n_in,
                              void* d_out, int out_size, void* d_ws, size_t ws_size,
                              hipStream_t stream) {
    const float* x_in  = (const float*)d_in[0];
    const int*   ei    = (const int*)d_in[1];
    const int*   batch = (const int*)d_in[2];
    const float* fc_w  = (const float*)d_in[3];
    const float* fc_b  = (const float*)d_in[4];
    const float* mg1_w = (const float*)d_in[5];
    const float* mg1_b = (const float*)d_in[6];
    const float* mg2_w = (const float*)d_in[7];
    const float* mg2_b = (const float*)d_in[8];
    const float* gate_w = (const float*)d_in[9];
    const float* gate_b = (const float*)d_in[10];
    const float* rd_w  = (const float*)d_in[11];
    const float* rd_b  = (const float*)d_in[12];
    const float* gru_wih = (const float*)d_in[13];
    const float* gru_whh = (const float*)d_in[14];
    const float* gru_bih = (const float*)d_in[15];
    const float* gru_bhh = (const float*)d_in[16];
    const float* bn_g  = (const float*)d_in[17];
    const float* bn_b  = (const float*)d_in[18];
    const float* clf1_w = (const float*)d_in[19];
    const float* clf1_b = (const float*)d_in[20];
    const float* clf2_w = (const float*)d_in[21];
    const float* clf2_b = (const float*)d_in[22];

    float* ws = (float*)d_ws;
    size_t off = 0;
    float* cur0 = ws + off; off += (size_t)N * Dk;
    float* cur1 = ws + off; off += (size_t)N * Dk;
    float* xa   = ws + off; off += (size_t)N * Dk;
    float* xb   = ws + off; off += (size_t)N * Dk;
    float* xr   = ws + off; off += (size_t)N * Dk;
    float* gf   = ws + off; off += (size_t)G * Dk;
    float* gfn  = ws + off; off += (size_t)G * Dk;
    float* gfr  = ws + off; off += (size_t)G * Dk;
    float* gfc  = ws + off; off += (size_t)G * Dk;
    float* giB  = ws + off; off += (size_t)G * 768;
    float* ghB  = ws + off; off += (size_t)G * 768;
    float* gnorm = ws + off; off += G;
    float* gcnt  = ws + off; off += G;
    float* xn   = ws + off; off += (size_t)G * Dk;
    float* hcl  = ws + off; off += (size_t)G * HID;
    float* wihT = ws + off; off += (size_t)768 * Dk;
    float* whhT = ws + off; off += (size_t)768 * Dk;
    int* ideg   = (int*)(ws + off); off += N;
    int* icur   = (int*)(ws + off); off += N;
    int* src_s  = (int*)(ws + off); off += E + 64;
    int* dst_s  = (int*)(ws + off); off += E + 64;
    int* gb_s   = (int*)(ws + off); off += E + 64;
    int* eperm  = (int*)(ws + off); off += E + 64;
    unsigned short* whi = (unsigned short*)(ws + off); off += (size_t)13 * 65536 / 2;
    unsigned short* wlo = (unsigned short*)(ws + off); off += (size_t)13 * 65536 / 2;

    float* out_logits = (float*)d_out;
    float* out_lgl = out_logits + (size_t)G * NCLS;
    float* out_ggl = out_lgl + (size_t)E * L;

    hipMemsetAsync(gf, 0, (size_t)G * Dk * 4, stream);
    hipMemsetAsync(gcnt, 0, (size_t)G * 4, stream);
    hipMemsetAsync(ideg, 0, (size_t)N * 4, stream);
    hipMemsetAsync(src_s + E, 0, 64 * 4, stream);   // pad for 64-edge tiles
    hipMemsetAsync(dst_s + E, 0, 64 * 4, stream);
    hipMemsetAsync(gb_s + E, 0, 64 * 4, stream);
    k_cnt<<<(N + 255) / 256, 256, 0, stream>>>(batch, gcnt);
    k_hist<<<(E + 255) / 256, 256, 0, stream>>>(ei, ideg);
    k_scan<<<1, 256, 0, stream>>>(ideg, icur);
    k_scatter<<<(E + 255) / 256, 256, 0, stream>>>(ei, batch, icur, src_s, dst_s, gb_s, eperm);
    k_transpose<<<(768 * Dk + 255) / 256, 256, 0, stream>>>(gru_wih, wihT, 768, Dk);
    k_transpose<<<(768 * Dk + 255) / 256, 256, 0, stream>>>(gru_whh, whhT, 768, Dk);

    // pre-pack GEMM weights into bf16 hi/lo fragment order
    {
        PackSrcs ps;
        for (int i = 0; i < L; ++i) {
            ps.p[0 + i] = mg2_w + (size_t)i * 65536;              // W2_i
            ps.p[3 + i] = gate_w + (size_t)i * 65536;             // Wg_i
            ps.p[6 + i] = mg1_w + (size_t)i * 196608;             // W1a_i
            ps.p[9 + i] = mg1_w + (size_t)i * 196608 + 65536;     // W1b_i
        }
        ps.p[12] = rd_w;                                          // rd_w node half
        k_packw<<<13 * 65536 / 256, 256, 0, stream>>>(ps, whi, wlo);
    }

    k_fc<<<(N + 31) / 32, 256, 0, stream>>>(x_in, fc_w, fc_b, cur0, N);

    float* cur = cur0;
    float* nxt = cur1;
    const int nblk64 = (N + 63) / 64;   // 157

    auto readout = [&](const float* xcur, int ridx) {
        k_gemm<8><<<dim3(G / 8, 1), 256, 0, stream>>>(gf, rd_w + 256 * Dk, Dk, rd_b, gfr, Dk, G);
        hipMemsetAsync(gfn, 0, (size_t)G * Dk * 4, stream);
        hipMemsetAsync(gnorm, 0, (size_t)G * 4, stream);
        k_readout_node<<<N / RNPB, 256, 0, stream>>>(xcur, xr, gfr, batch, gfn, gnorm);
        k_gemm<8><<<dim3(G / 8, 3), 256, 0, stream>>>(gfn, wihT, 768, gru_bih, giB, 768, G);
        k_gemm<8><<<dim3(G / 8, 3), 256, 0, stream>>>(gf, whhT, 768, gru_bhh, ghB, 768, G);
        k_gru_ew<<<G, 256, 0, stream>>>(giB, ghB, gf);
        k_ggl<<<1, 64, 0, stream>>>(gnorm, gcnt, out_ggl + ridx);
    };

    for (int i = 0; i < L; ++i) {
        // xa = cur@W1a, xb = cur@W1b, xr = cur@rd_w  (MFMA, one A-stage)
        k_mm_mf<3><<<nblk64, 256, 0, stream>>>(
            cur, N,
            whi + (size_t)(6 + i) * 65536, wlo + (size_t)(6 + i) * 65536,
            whi + (size_t)(9 + i) * 65536, wlo + (size_t)(9 + i) * 65536,
            whi + (size_t)12 * 65536, wlo + (size_t)12 * 65536,
            xa, xb, xr);
        readout(cur, i);
        k_gemm<8><<<dim3(G / 8, 1), 256, 0, stream>>>(gf, mg1_w + (size_t)i * 196608 + 131072,
                                                      Dk, mg1_b + i * Dk, gfc, Dk, G);
        hipMemsetAsync(nxt, 0, (size_t)N * Dk * 4, stream);
        k_edge_mf<<<NEBLK, 256, 0, stream>>>(
            xa, xb, gfc, src_s, dst_s, gb_s, eperm,
            whi + (size_t)i * 65536, wlo + (size_t)i * 65536, mg2_b + i * Dk,
            whi + (size_t)(3 + i) * 65536, wlo + (size_t)(3 + i) * 65536, gate_b + i * Dk,
            nxt, out_lgl, i);
        float* tmp = cur; cur = nxt; nxt = tmp;
    }
    k_mm_mf<1><<<nblk64, 256, 0, stream>>>(
        cur, N,
        whi + (size_t)12 * 65536, wlo + (size_t)12 * 65536,
        nullptr, nullptr, nullptr, nullptr,
        xr, nullptr, nullptr);
    readout(cur, L);

    k_bn<<<1, 256, 0, stream>>>(gf, bn_g, bn_b, xn);
    k_clf1<<<G, 256, 0, stream>>>(xn, clf1_w, clf1_b, hcl);
    k_clf2<<<G, 256, 0, stream>>>(hcl, clf2_w, clf2_b, out_logits);
}

// Round 11
// 1281.171 us; speedup vs baseline: 1.8799x; 1.2548x over previous
//
#include <hip/hip_runtime.h>
#include <math.h>

// Problem constants (match reference)
constexpr int N = 10000, E = 100000, G = 64;
constexpr int F = 64, Dk = 256, L = 3;
constexpr int HID = 256, NCLS = 10;

typedef __attribute__((ext_vector_type(8))) short short8v;   // 8 bf16 (4 VGPR)
typedef __attribute__((ext_vector_type(4))) float f32x4;

__device__ __forceinline__ float sigmoidf_(float x) {
    return 1.0f / (1.0f + __expf(-x));
}
__device__ __forceinline__ float leakyf_(float v) {
    return v > 0.0f ? v : 0.01f * v;
}

// bf16 round-to-nearest-even, bit-level
__device__ __forceinline__ unsigned short f2bf(float f) {
    unsigned int u = __float_as_uint(f);
    u = (u + 0x7fffu + ((u >> 16) & 1u)) >> 16;
    return (unsigned short)u;
}
__device__ __forceinline__ float bf2f(unsigned short b) {
    return __uint_as_float(((unsigned int)b) << 16);
}
__device__ __forceinline__ void split_bf16(float v, unsigned short& hb, unsigned short& lb) {
    hb = f2bf(v);
    lb = f2bf(v - bf2f(hb));
}

__device__ __forceinline__ f32x4 mfma16(short8v a, short8v b, f32x4 c) {
    return __builtin_amdgcn_mfma_f32_16x16x32_bf16(a, b, c, 0, 0, 0);
}

// ---------------------------------------------------------------------------
// Edge sort by dst: histogram -> single-block scan -> scatter.
// ---------------------------------------------------------------------------
__global__ void k_hist(const int* __restrict__ ei, int* __restrict__ deg) {
    const int e = blockIdx.x * 256 + threadIdx.x;
    if (e < E) atomicAdd(&deg[ei[E + e]], 1);
}

__global__ void k_scan(const int* __restrict__ deg, int* __restrict__ cursor) {
    __shared__ int part[256];
    __shared__ int off[256];
    const int t = threadIdx.x;
    const int base = t * 40;  // 256*40 = 10240 >= N
    int s = 0;
    for (int i = 0; i < 40; ++i) {
        const int idx = base + i;
        if (idx < N) s += deg[idx];
    }
    part[t] = s;
    __syncthreads();
    if (t == 0) {
        int acc = 0;
        for (int i = 0; i < 256; ++i) { off[i] = acc; acc += part[i]; }
    }
    __syncthreads();
    int run = off[t];
    for (int i = 0; i < 40; ++i) {
        const int idx = base + i;
        if (idx < N) { cursor[idx] = run; run += deg[idx]; }
    }
}

__global__ void k_scatter(const int* __restrict__ ei, const int* __restrict__ batch,
                          int* __restrict__ cursor, int* __restrict__ src_s,
                          int* __restrict__ dst_s, int* __restrict__ gb_s,
                          int* __restrict__ eperm) {
    const int e = blockIdx.x * 256 + threadIdx.x;
    if (e < E) {
        const int d = ei[E + e];
        const int pos = atomicAdd(&cursor[d], 1);
        dst_s[pos] = d;
        src_s[pos] = ei[e];
        gb_s[pos] = batch[d];
        eperm[pos] = e;
    }
}

// graph start offsets from sorted batch: gstart[g] = first node of graph g,
// gstart[G] = N.  Handles empty graphs.
__global__ void k_gstart(const int* __restrict__ batch, int* __restrict__ gstart) {
    const int n = blockIdx.x * 256 + threadIdx.x;
    if (n >= N) return;
    const int b = batch[n];
    if (n == 0) {
        for (int g = 0; g <= b; ++g) gstart[g] = 0;
    } else {
        const int bp = batch[n - 1];
        for (int g = bp + 1; g <= b; ++g) gstart[g] = n;
    }
    if (n == N - 1) {
        for (int g = b + 1; g <= G; ++g) gstart[g] = N;
    }
}

// ---------------------------------------------------------------------------
// Weight pre-pack: 13 matrices 256x256 -> bf16 hi/lo, per-lane MFMA B-frag
// order: out[(((nt*8)+ks)*64 + l)*8 + i] = W[k][c], c = nt*16+(l&15),
// k = ks*32 + (l>>4)*8 + i.
// mats: 0-2 W2_i, 3-5 Wg_i, 6-8 W1a_i, 9-11 W1b_i, 12 rd_w(node half)
// ---------------------------------------------------------------------------
struct PackSrcs { const float* p[13]; };

__global__ void k_packw(PackSrcs ps, unsigned short* __restrict__ whi,
                        unsigned short* __restrict__ wlo) {
    const int tid = blockIdx.x * 256 + threadIdx.x;   // 13*65536 total
    const int mat = tid >> 16;
    const int f = tid & 65535;
    const int i = f & 7, l = (f >> 3) & 63, ks = (f >> 9) & 7, nt = (f >> 12) & 15;
    const int k = ks * 32 + ((l >> 4) << 3) + i;
    const int c = nt * 16 + (l & 15);
    const float v = ps.p[mat][k * 256 + c];
    unsigned short hb, lb;
    split_bf16(v, hb, lb);
    whi[tid] = hb;
    wlo[tid] = lb;
}

// ---------------------------------------------------------------------------
// MFMA fused edge kernel, 64 edges/block (edges pre-sorted by dst).
// ---------------------------------------------------------------------------
constexpr int NEBLK = (E + 63) / 64;   // 1563 (tail block half-valid)

__global__ __launch_bounds__(256, 2) void k_edge_mf(
    const float* __restrict__ xa, const float* __restrict__ xb,
    const float* __restrict__ gfc,
    const int* __restrict__ src_s, const int* __restrict__ dst_s,
    const int* __restrict__ gb_s, const int* __restrict__ eperm,
    const unsigned short* __restrict__ w2h, const unsigned short* __restrict__ w2l,
    const float* __restrict__ b2,
    const unsigned short* __restrict__ wgh, const unsigned short* __restrict__ wgl,
    const float* __restrict__ bg,
    float* __restrict__ nxt, float* __restrict__ lgl, int layer) {
    __shared__ short8v ahv[2048];   // 32 KB  A hi (64 rows x 32 frags)
    __shared__ short8v alv[2048];   // 32 KB  A lo
    __shared__ int sdst[64];
    __shared__ float prow[2][64];

    const int t = threadIdx.x;
    constexpr int qq = NEBLK / 8, rr = NEBLK % 8;
    const int orig = blockIdx.x;
    const int xcd = orig & 7, pos = orig >> 3;
    const int bid = (xcd < rr ? xcd * (qq + 1) : rr * (qq + 1) + (xcd - rr) * qq) + pos;
    const int e0 = bid * 64;

    if (t < 64) sdst[t] = dst_s[e0 + t];

    {   // h1 build: 4 threads/row, 8x 8-elem chunks each, split to LDS
        const int r = t >> 2, l4 = t & 3;
        const int d = dst_s[e0 + r], s = src_s[e0 + r], b = gb_s[e0 + r];
        const float4* pa = (const float4*)(xa + (size_t)d * Dk);
        const float4* pb = (const float4*)(xb + (size_t)s * Dk);
        const float4* pg = (const float4*)(gfc + (size_t)b * Dk);
        const int rsw = r & 7;
#pragma unroll
        for (int j = 0; j < 8; ++j) {
            const int k8 = l4 + 4 * j;
            const int ci = k8 * 2;
            const float4 a0 = pa[ci], a1 = pa[ci + 1];
            const float4 b0 = pb[ci], b1 = pb[ci + 1];
            const float4 g0 = pg[ci], g1 = pg[ci + 1];
            float v[8];
            v[0] = leakyf_(a0.x + b0.x + g0.x); v[1] = leakyf_(a0.y + b0.y + g0.y);
            v[2] = leakyf_(a0.z + b0.z + g0.z); v[3] = leakyf_(a0.w + b0.w + g0.w);
            v[4] = leakyf_(a1.x + b1.x + g1.x); v[5] = leakyf_(a1.y + b1.y + g1.y);
            v[6] = leakyf_(a1.z + b1.z + g1.z); v[7] = leakyf_(a1.w + b1.w + g1.w);
            short8v hv, lv;
#pragma unroll
            for (int ii = 0; ii < 8; ++ii) {
                unsigned short hb, lb;
                split_bf16(v[ii], hb, lb);
                hv[ii] = (short)hb; lv[ii] = (short)lb;
            }
            const int fi = (r * 32 + k8) ^ rsw;
            ahv[fi] = hv; alv[fi] = lv;
        }
    }
    __syncthreads();

    const int l = t & 63, wid = t >> 6;
    const int wr = wid >> 1, wc = wid & 1;
    const int rb = wr * 32, cb = wc * 128;
    const int colbase = cb + (l & 15);
    const int akb = l >> 4;
    const int asw = l & 7;
    const int ntg0 = cb >> 4;
    const int arow0 = rb + (l & 15);

    const short8v* W2H = (const short8v*)w2h;
    const short8v* W2L = (const short8v*)w2l;
    const short8v* WGH = (const short8v*)wgh;
    const short8v* WGL = (const short8v*)wgl;

    f32x4 acc[2][8];
    // ================= GEMM1: msg = leaky(h1 @ W2 + b2) =================
#pragma unroll
    for (int mf = 0; mf < 2; ++mf)
#pragma unroll
        for (int nt = 0; nt < 8; ++nt) {
            const float bb = b2[colbase + nt * 16];
            acc[mf][nt] = f32x4{bb, bb, bb, bb};
        }
#pragma unroll
    for (int ks = 0; ks < 8; ++ks) {
        short8v ah[2], al[2];
#pragma unroll
        for (int mf = 0; mf < 2; ++mf) {
            const int ai = ((arow0 + mf * 16) * 32 + ks * 4 + akb) ^ asw;
            ah[mf] = ahv[ai]; al[mf] = alv[ai];
        }
#pragma unroll
        for (int ntc = 0; ntc < 2; ++ntc) {
            short8v bh[4], bl[4];
#pragma unroll
            for (int q = 0; q < 4; ++q) {
                const int wi = ((ntg0 + ntc * 4 + q) * 8 + ks) * 64 + l;
                bh[q] = W2H[wi]; bl[q] = W2L[wi];
            }
#pragma unroll
            for (int q = 0; q < 4; ++q)
#pragma unroll
                for (int mf = 0; mf < 2; ++mf) {
                    const int nt = ntc * 4 + q;
                    acc[mf][nt] = mfma16(ah[mf], bh[q], acc[mf][nt]);
                    acc[mf][nt] = mfma16(al[mf], bh[q], acc[mf][nt]);
                    acc[mf][nt] = mfma16(ah[mf], bl[q], acc[mf][nt]);
                }
        }
    }
    f32x4 msg[2][8];
#pragma unroll
    for (int mf = 0; mf < 2; ++mf)
#pragma unroll
        for (int nt = 0; nt < 8; ++nt)
#pragma unroll
            for (int r = 0; r < 4; ++r) msg[mf][nt][r] = leakyf_(acc[mf][nt][r]);
    __syncthreads();
    {   // write msg hi/lo back to LDS in A-layout (swizzled)
        unsigned short* AH = (unsigned short*)ahv;
        unsigned short* AL = (unsigned short*)alv;
#pragma unroll
        for (int mf = 0; mf < 2; ++mf) {
            const int r0w = rb + mf * 16 + akb * 4;
#pragma unroll
            for (int r = 0; r < 4; ++r) {
                const int row = r0w + r;
                const int sw = (row & 7) << 3;
#pragma unroll
                for (int nt = 0; nt < 8; ++nt) {
                    unsigned short hb, lb;
                    split_bf16(msg[mf][nt][r], hb, lb);
                    const int si = (row * 256 + colbase + nt * 16) ^ sw;
                    AH[si] = hb; AL[si] = lb;
                }
            }
        }
    }
    __syncthreads();

    // ================= GEMM2: gp = msg @ Wg + bg =================
#pragma unroll
    for (int mf = 0; mf < 2; ++mf)
#pragma unroll
        for (int nt = 0; nt < 8; ++nt) {
            const float bb = bg[colbase + nt * 16];
            acc[mf][nt] = f32x4{bb, bb, bb, bb};
        }
#pragma unroll
    for (int ks = 0; ks < 8; ++ks) {
        short8v ah[2], al[2];
#pragma unroll
        for (int mf = 0; mf < 2; ++mf) {
            const int ai = ((arow0 + mf * 16) * 32 + ks * 4 + akb) ^ asw;
            ah[mf] = ahv[ai]; al[mf] = alv[ai];
        }
#pragma unroll
        for (int ntc = 0; ntc < 2; ++ntc) {
            short8v bh[4], bl[4];
#pragma unroll
            for (int q = 0; q < 4; ++q) {
                const int wi = ((ntg0 + ntc * 4 + q) * 8 + ks) * 64 + l;
                bh[q] = WGH[wi]; bl[q] = WGL[wi];
            }
#pragma unroll
            for (int q = 0; q < 4; ++q)
#pragma unroll
                for (int mf = 0; mf < 2; ++mf) {
                    const int nt = ntc * 4 + q;
                    acc[mf][nt] = mfma16(ah[mf], bh[q], acc[mf][nt]);
                    acc[mf][nt] = mfma16(al[mf], bh[q], acc[mf][nt]);
                    acc[mf][nt] = mfma16(ah[mf], bl[q], acc[mf][nt]);
                }
        }
    }

    // ---- epilogue ----
#pragma unroll
    for (int mf = 0; mf < 2; ++mf) {
        float vs[8];
#pragma unroll
        for (int nt = 0; nt < 8; ++nt) vs[nt] = 0.0f;
        const int r0w = rb + mf * 16 + akb * 4;
#pragma unroll
        for (int r = 0; r < 4; ++r) {
            const int row = r0w + r;
            const int d = sdst[row];
            float sr = 0.0f;
#pragma unroll
            for (int nt = 0; nt < 8; ++nt) {
                const float m = msg[mf][nt][r];
                const float lw = sigmoidf_(acc[mf][nt][r]) * m;
                vs[nt] += lw * m;
                sr += lw * lw;
            }
            const bool flush = (r == 3) || (sdst[row + 1] != d);
            if (flush) {
                if (e0 + row < E) {
                    float* basep = nxt + (size_t)d * Dk;
#pragma unroll
                    for (int nt = 0; nt < 8; ++nt)
                        atomicAdd(basep + colbase + nt * 16, vs[nt]);
                }
#pragma unroll
                for (int nt = 0; nt < 8; ++nt) vs[nt] = 0.0f;
            }
            sr += __shfl_xor(sr, 1, 64);
            sr += __shfl_xor(sr, 2, 64);
            sr += __shfl_xor(sr, 4, 64);
            sr += __shfl_xor(sr, 8, 64);
            if ((l & 15) == 0) prow[wc][row] = sr;
        }
    }
    __syncthreads();
    if (t < 64 && e0 + t < E)
        lgl[(size_t)eperm[e0 + t] * L + layer] = sqrtf(prow[0][t] + prow[1][t]);
}

// ---------------------------------------------------------------------------
// MFMA node GEMM, 32 rows/block (313 blocks -> >1.2 blocks/CU), NW packed
// weight streams sharing one A tile:  C_w[M,256] = A[M,256] @ W_w
// ---------------------------------------------------------------------------
template <int NW>
__global__ __launch_bounds__(256, 2) void k_mm_mf(
    const float* __restrict__ A, int M,
    const unsigned short* __restrict__ h0, const unsigned short* __restrict__ l0,
    const unsigned short* __restrict__ h1, const unsigned short* __restrict__ l1,
    const unsigned short* __restrict__ h2, const unsigned short* __restrict__ l2,
    float* __restrict__ C0, float* __restrict__ C1, float* __restrict__ C2) {
    __shared__ short8v ahv[1024];
    __shared__ short8v alv[1024];
    const int t = threadIdx.x;
    const int r0 = blockIdx.x * 32;

    {   // stage A rows (clamped for tail), split hi/lo
        const int r = t >> 3, l8 = t & 7;
        int row = r0 + r;
        if (row >= M) row = M - 1;
        const float4* pa = (const float4*)(A + (size_t)row * Dk);
        const int rsw = r & 7;
#pragma unroll
        for (int j = 0; j < 4; ++j) {
            const int k8 = l8 + 8 * j;
            const int ci = k8 * 2;
            const float4 a0 = pa[ci], a1 = pa[ci + 1];
            const float v[8] = {a0.x, a0.y, a0.z, a0.w, a1.x, a1.y, a1.z, a1.w};
            short8v hv, lv;
#pragma unroll
            for (int ii = 0; ii < 8; ++ii) {
                unsigned short hb, lb;
                split_bf16(v[ii], hb, lb);
                hv[ii] = (short)hb; lv[ii] = (short)lb;
            }
            const int fi = (r * 32 + k8) ^ rsw;
            ahv[fi] = hv; alv[fi] = lv;
        }
    }
    __syncthreads();

    const int l = t & 63, wid = t >> 6;
    const int wr = wid >> 1, wc = wid & 1;
    const int rb = wr * 16, cb = wc * 128;
    const int colbase = cb + (l & 15);
    const int arow = rb + (l & 15);
    const int art = arow * 32, asw = arow & 7;
    const int akb = l >> 4;
    const int ntg0 = cb >> 4;

    const unsigned short* hs[3] = {h0, h1, h2};
    const unsigned short* ls[3] = {l0, l1, l2};
    float* Cs[3] = {C0, C1, C2};
#pragma unroll
    for (int w = 0; w < NW; ++w) {
        const short8v* WH = (const short8v*)hs[w];
        const short8v* WL = (const short8v*)ls[w];
        f32x4 acc[8];
#pragma unroll
        for (int nt = 0; nt < 8; ++nt) acc[nt] = f32x4{0.f, 0.f, 0.f, 0.f};
#pragma unroll
        for (int ks = 0; ks < 8; ++ks) {
            const int ai = (art + ks * 4 + akb) ^ asw;
            const short8v ah = ahv[ai];
            const short8v al = alv[ai];
            short8v bh[8], bl[8];
#pragma unroll
            for (int nt = 0; nt < 8; ++nt) {
                const int wi = ((ntg0 + nt) * 8 + ks) * 64 + l;
                bh[nt] = WH[wi]; bl[nt] = WL[wi];
            }
#pragma unroll
            for (int nt = 0; nt < 8; ++nt) acc[nt] = mfma16(ah, bh[nt], acc[nt]);
#pragma unroll
            for (int nt = 0; nt < 8; ++nt) acc[nt] = mfma16(al, bh[nt], acc[nt]);
#pragma unroll
            for (int nt = 0; nt < 8; ++nt) acc[nt] = mfma16(ah, bl[nt], acc[nt]);
        }
        float* Cp = Cs[w];
        const int r0w = rb + (l >> 4) * 4;
#pragma unroll
        for (int r = 0; r < 4; ++r) {
            const int row = r0 + r0w + r;
            if (row < M) {
#pragma unroll
                for (int nt = 0; nt < 8; ++nt)
                    Cp[(size_t)row * Dk + colbase + nt * 16] = acc[nt][r];
            }
        }
    }
}

// fc: C[M,256] = A[M,64] @ B[64,256] + bias
__global__ void k_fc(const float* __restrict__ A, const float* __restrict__ B,
                     const float* __restrict__ bias, float* __restrict__ C, int M) {
    __shared__ float Ald[32][F];
    const int t = threadIdx.x;
    const int r0 = blockIdx.x * 32;
    for (int i = t; i < 32 * F; i += 256) {
        int r = i >> 6, k = i & 63;
        Ald[r][k] = (r0 + r < M) ? A[(size_t)(r0 + r) * F + k] : 0.0f;
    }
    __syncthreads();
    const int c = t;
    float acc[32];
    const float bi = bias[c];
#pragma unroll
    for (int e = 0; e < 32; ++e) acc[e] = bi;
    for (int k = 0; k < F; k += 4) {
        const float w0 = B[(size_t)(k + 0) * Dk + c];
        const float w1 = B[(size_t)(k + 1) * Dk + c];
        const float w2 = B[(size_t)(k + 2) * Dk + c];
        const float w3 = B[(size_t)(k + 3) * Dk + c];
#pragma unroll
        for (int e = 0; e < 32; ++e) {
            const float4 a = *reinterpret_cast<const float4*>(&Ald[e][k]);
            acc[e] = fmaf(a.x, w0, acc[e]);
            acc[e] = fmaf(a.y, w1, acc[e]);
            acc[e] = fmaf(a.z, w2, acc[e]);
            acc[e] = fmaf(a.w, w3, acc[e]);
        }
    }
#pragma unroll
    for (int e = 0; e < 32; ++e)
        if (r0 + e < M) C[(size_t)(r0 + e) * Dk + c] = acc[e];
}

// ---------------------------------------------------------------------------
// Fully fused readout: one block per graph (G=64 blocks, 256 thr = 4 waves).
//   gfr = gf[g] @ rd_w[256:] + rd_b
//   loop nodes n in [gstart[g], gstart[g+1]):
//     gw = sigmoid(xr[n] + gfr); gfn += gw*x[n]; gn += ||gw||
//   gf[g] = GRU(gfn, gf[g]);  ggl += (gn/cnt)/G  (atomic)
//   optional: gfc[g] = gf_new @ W1c + b1   (next conv block's graph term)
// ---------------------------------------------------------------------------
__global__ __launch_bounds__(256) void k_readout_all(
    const float* __restrict__ x, const float* __restrict__ xr,
    const int* __restrict__ gstart,
    const float* __restrict__ rdwg, const float* __restrict__ rd_b,
    const float* __restrict__ wihT, const float* __restrict__ whhT,
    const float* __restrict__ bih, const float* __restrict__ bhh,
    float* __restrict__ gf,
    const float* __restrict__ w1c, const float* __restrict__ b1,
    float* __restrict__ gfc, float* __restrict__ ggl_out) {
    __shared__ float sgf[Dk];      // old gf row
    __shared__ float sgfr[Dk];     // gfr row (later reused for gf_new)
    __shared__ float part[4][Dk];  // per-wave gfn partials
    __shared__ float sgfn[Dk];
    __shared__ float rsw4[4];

    const int g = blockIdx.x, t = threadIdx.x;
    const int lane = t & 63, wv = t >> 6;
    sgf[t] = gf[(size_t)g * Dk + t];
    __syncthreads();

    // gfr[c] = sum_k sgf[k] * rdwg[k][c] + rd_b[c]
    {
        float acc = rd_b[t];
        for (int k = 0; k < Dk; k += 4) {
            const float4 a = *(const float4*)(&sgf[k]);
            acc = fmaf(a.x, rdwg[(size_t)(k + 0) * Dk + t], acc);
            acc = fmaf(a.y, rdwg[(size_t)(k + 1) * Dk + t], acc);
            acc = fmaf(a.z, rdwg[(size_t)(k + 2) * Dk + t], acc);
            acc = fmaf(a.w, rdwg[(size_t)(k + 3) * Dk + t], acc);
        }
        sgfr[t] = acc;
    }
    __syncthreads();

    // node loop: wave wv handles nodes ns+wv, +4, ...; lane covers cols lane*4..+3
    const int ns = gstart[g], ne = gstart[g + 1];
    const int c4 = lane * 4;
    const float4 gfr4 = *(const float4*)(&sgfr[c4]);
    float p0 = 0.f, p1 = 0.f, p2 = 0.f, p3 = 0.f;
    float rs = 0.f;
    for (int n = ns + wv; n < ne; n += 4) {
        const float4 vr = *(const float4*)(xr + (size_t)n * Dk + c4);
        const float4 vx = *(const float4*)(x + (size_t)n * Dk + c4);
        const float g0 = sigmoidf_(vr.x + gfr4.x);
        const float g1 = sigmoidf_(vr.y + gfr4.y);
        const float g2 = sigmoidf_(vr.z + gfr4.z);
        const float g3 = sigmoidf_(vr.w + gfr4.w);
        p0 = fmaf(g0, vx.x, p0);
        p1 = fmaf(g1, vx.y, p1);
        p2 = fmaf(g2, vx.z, p2);
        p3 = fmaf(g3, vx.w, p3);
        float ss = g0 * g0 + g1 * g1 + g2 * g2 + g3 * g3;
        ss += __shfl_xor(ss, 1, 64);
        ss += __shfl_xor(ss, 2, 64);
        ss += __shfl_xor(ss, 4, 64);
        ss += __shfl_xor(ss, 8, 64);
        ss += __shfl_xor(ss, 16, 64);
        ss += __shfl_xor(ss, 32, 64);
        if (lane == 0) rs += sqrtf(ss);
    }
    *(float4*)(&part[wv][c4]) = make_float4(p0, p1, p2, p3);
    if (lane == 0) rsw4[wv] = rs;
    __syncthreads();
    sgfn[t] = part[0][t] + part[1][t] + part[2][t] + part[3][t];
    __syncthreads();

    // GRU for col t (wihT/whhT are [256][768]: row k contiguous over outputs)
    float gi0 = bih[t], gi1 = bih[256 + t], gi2 = bih[512 + t];
    float gh0 = bhh[t], gh1 = bhh[256 + t], gh2 = bhh[512 + t];
#pragma unroll 4
    for (int k = 0; k < Dk; ++k) {
        const float fk = sgfn[k], hk = sgf[k];
        const float* wi = wihT + (size_t)k * 768;
        const float* wh = whhT + (size_t)k * 768;
        gi0 = fmaf(fk, wi[t], gi0);
        gi1 = fmaf(fk, wi[256 + t], gi1);
        gi2 = fmaf(fk, wi[512 + t], gi2);
        gh0 = fmaf(hk, wh[t], gh0);
        gh1 = fmaf(hk, wh[256 + t], gh1);
        gh2 = fmaf(hk, wh[512 + t], gh2);
    }
    const float r = sigmoidf_(gi0 + gh0);
    const float z = sigmoidf_(gi1 + gh1);
    const float nn = tanhf(gi2 + r * gh2);
    const float hnew = (1.0f - z) * nn + z * sgf[t];
    gf[(size_t)g * Dk + t] = hnew;

    if (t == 0) {
        const float gn = rsw4[0] + rsw4[1] + rsw4[2] + rsw4[3];
        const float cnt = (float)(ne - ns);
        atomicAdd(ggl_out, (gn / fmaxf(cnt, 1.0f)) * (1.0f / G));
    }

    // optional fused gfc = gf_new @ W1c + b1
    if (gfc != nullptr) {
        __syncthreads();
        sgfr[t] = hnew;          // reuse sgfr for gf_new
        __syncthreads();
        float acc = b1[t];
        for (int k = 0; k < Dk; k += 4) {
            const float4 a = *(const float4*)(&sgfr[k]);
            acc = fmaf(a.x, w1c[(size_t)(k + 0) * Dk + t], acc);
            acc = fmaf(a.y, w1c[(size_t)(k + 1) * Dk + t], acc);
            acc = fmaf(a.z, w1c[(size_t)(k + 2) * Dk + t], acc);
            acc = fmaf(a.w, w1c[(size_t)(k + 3) * Dk + t], acc);
        }
        gfc[(size_t)g * Dk + t] = acc;
    }
}

// transpose in[rows,cols] -> out[cols,rows]
__global__ void k_transpose(const float* __restrict__ in, float* __restrict__ out,
                            int rows, int cols) {
    const int idx = blockIdx.x * 256 + threadIdx.x;
    if (idx < rows * cols) {
        const int r = idx / cols, c = idx % cols;
        out[(size_t)c * rows + r] = in[(size_t)r * cols + c];
    }
}

// BatchNorm (training stats over G graphs) -> xn
__global__ void k_bn(const float* __restrict__ gf, const float* __restrict__ bg,
                     const float* __restrict__ bb, float* __restrict__ xn) {
    const int f = threadIdx.x;
    float mu = 0.0f;
    for (int g = 0; g < G; ++g) mu += gf[(size_t)g * Dk + f];
    mu *= (1.0f / G);
    float var = 0.0f;
    for (int g = 0; g < G; ++g) {
        const float d = gf[(size_t)g * Dk + f] - mu;
        var += d * d;
    }
    var *= (1.0f / G);
    const float inv = (1.0f / sqrtf(var + 1e-5f)) * bg[f];
    const float bet = bb[f];
    for (int g = 0; g < G; ++g)
        xn[(size_t)g * Dk + f] = (gf[(size_t)g * Dk + f] - mu) * inv + bet;
}

__global__ void k_clf1(const float* __restrict__ xn, const float* __restrict__ W,
                       const float* __restrict__ b, float* __restrict__ out) {
    __shared__ float row[Dk];
    const int g = blockIdx.x, t = threadIdx.x;
    row[t] = xn[(size_t)g * Dk + t];
    __syncthreads();
    float acc = b[t];
    for (int k = 0; k < Dk; k += 4) {
        const float4 a = *reinterpret_cast<const float4*>(&row[k]);
        acc = fmaf(a.x, W[(size_t)(k + 0) * HID + t], acc);
        acc = fmaf(a.y, W[(size_t)(k + 1) * HID + t], acc);
        acc = fmaf(a.z, W[(size_t)(k + 2) * HID + t], acc);
        acc = fmaf(a.w, W[(size_t)(k + 3) * HID + t], acc);
    }
    out[(size_t)g * HID + t] = leakyf_(acc);
}

__global__ void k_clf2(const float* __restrict__ h, const float* __restrict__ W,
                       const float* __restrict__ b, float* __restrict__ out) {
    __shared__ float row[HID];
    __shared__ float lg[NCLS];
    const int g = blockIdx.x, t = threadIdx.x;
    row[t] = h[(size_t)g * HID + t];
    __syncthreads();
    if (t < NCLS) {
        float acc = b[t];
        for (int k = 0; k < HID; ++k) acc = fmaf(row[k], W[(size_t)k * NCLS + t], acc);
        lg[t] = acc;
    }
    __syncthreads();
    if (t == 0) {
        float m = lg[0];
        for (int i = 1; i < NCLS; ++i) m = fmaxf(m, lg[i]);
        float s = 0.0f;
        for (int i = 0; i < NCLS; ++i) s += expf(lg[i] - m);
        const float ls = logf(s) + m;
        for (int i = 0; i < NCLS; ++i) out[(size_t)g * NCLS + i] = lg[i] - ls;
    }
}

// ---------------------------------------------------------------------------
extern "C" void kernel_launch(void* const* d_in, const int* in_sizes, int n_in,
                              void* d_out, int out_size, void* d_ws, size_t ws_size,
                              hipStream_t stream) {
    const float* x_in  = (const float*)d_in[0];
    const int*   ei    = (const int*)d_in[1];
    const int*   batch = (const int*)d_in[2];
    const float* fc_w  = (const float*)d_in[3];
    const float* fc_b  = (const float*)d_in[4];
    const float* mg1_w = (const float*)d_in[5];
    const float* mg1_b = (const float*)d_in[6];
    const float* mg2_w = (const float*)d_in[7];
    const float* mg2_b = (const float*)d_in[8];
    const float* gate_w = (const float*)d_in[9];
    const float* gate_b = (const float*)d_in[10];
    const float* rd_w  = (const float*)d_in[11];
    const float* rd_b  = (const float*)d_in[12];
    const float* gru_wih = (const float*)d_in[13];
    const float* gru_whh = (const float*)d_in[14];
    const float* gru_bih = (const float*)d_in[15];
    const float* gru_bhh = (const float*)d_in[16];
    const float* bn_g  = (const float*)d_in[17];
    const float* bn_b  = (const float*)d_in[18];
    const float* clf1_w = (const float*)d_in[19];
    const float* clf1_b = (const float*)d_in[20];
    const float* clf2_w = (const float*)d_in[21];
    const float* clf2_b = (const float*)d_in[22];

    float* ws = (float*)d_ws;
    size_t off = 0;
    float* cur0 = ws + off; off += (size_t)N * Dk;
    float* cur1 = ws + off; off += (size_t)N * Dk;
    float* xa   = ws + off; off += (size_t)N * Dk;
    float* xb   = ws + off; off += (size_t)N * Dk;
    float* xr   = ws + off; off += (size_t)N * Dk;
    float* gf   = ws + off; off += (size_t)G * Dk;
    float* gfc  = ws + off; off += (size_t)G * Dk;
    float* xn   = ws + off; off += (size_t)G * Dk;
    float* hcl  = ws + off; off += (size_t)G * HID;
    float* wihT = ws + off; off += (size_t)768 * Dk;
    float* whhT = ws + off; off += (size_t)768 * Dk;
    int* ideg   = (int*)(ws + off); off += N;
    int* icur   = (int*)(ws + off); off += N;
    int* gstart = (int*)(ws + off); off += (G + 1);
    int* src_s  = (int*)(ws + off); off += E + 64;
    int* dst_s  = (int*)(ws + off); off += E + 64;
    int* gb_s   = (int*)(ws + off); off += E + 64;
    int* eperm  = (int*)(ws + off); off += E + 64;
    unsigned short* whi = (unsigned short*)(ws + off); off += (size_t)13 * 65536 / 2;
    unsigned short* wlo = (unsigned short*)(ws + off); off += (size_t)13 * 65536 / 2;

    float* out_logits = (float*)d_out;
    float* out_lgl = out_logits + (size_t)G * NCLS;
    float* out_ggl = out_lgl + (size_t)E * L;

    hipMemsetAsync(gf, 0, (size_t)G * Dk * 4, stream);
    hipMemsetAsync(ideg, 0, (size_t)N * 4, stream);
    hipMemsetAsync(src_s + E, 0, 64 * 4, stream);   // pad for 64-edge tiles
    hipMemsetAsync(dst_s + E, 0, 64 * 4, stream);
    hipMemsetAsync(gb_s + E, 0, 64 * 4, stream);
    hipMemsetAsync(out_ggl, 0, (L + 1) * 4, stream);
    k_gstart<<<(N + 255) / 256, 256, 0, stream>>>(batch, gstart);
    k_hist<<<(E + 255) / 256, 256, 0, stream>>>(ei, ideg);
    k_scan<<<1, 256, 0, stream>>>(ideg, icur);
    k_scatter<<<(E + 255) / 256, 256, 0, stream>>>(ei, batch, icur, src_s, dst_s, gb_s, eperm);
    k_transpose<<<(768 * Dk + 255) / 256, 256, 0, stream>>>(gru_wih, wihT, 768, Dk);
    k_transpose<<<(768 * Dk + 255) / 256, 256, 0, stream>>>(gru_whh, whhT, 768, Dk);

    // pre-pack GEMM weights into bf16 hi/lo fragment order
    {
        PackSrcs ps;
        for (int i = 0; i < L; ++i) {
            ps.p[0 + i] = mg2_w + (size_t)i * 65536;              // W2_i
            ps.p[3 + i] = gate_w + (size_t)i * 65536;             // Wg_i
            ps.p[6 + i] = mg1_w + (size_t)i * 196608;             // W1a_i
            ps.p[9 + i] = mg1_w + (size_t)i * 196608 + 65536;     // W1b_i
        }
        ps.p[12] = rd_w;                                          // rd_w node half
        k_packw<<<13 * 65536 / 256, 256, 0, stream>>>(ps, whi, wlo);
    }

    k_fc<<<(N + 31) / 32, 256, 0, stream>>>(x_in, fc_w, fc_b, cur0, N);

    float* cur = cur0;
    float* nxt = cur1;
    const int nblk32 = (N + 31) / 32;   // 313

    for (int i = 0; i < L; ++i) {
        // xa = cur@W1a, xb = cur@W1b, xr = cur@rd_w  (MFMA, one A-stage)
        k_mm_mf<3><<<nblk32, 256, 0, stream>>>(
            cur, N,
            whi + (size_t)(6 + i) * 65536, wlo + (size_t)(6 + i) * 65536,
            whi + (size_t)(9 + i) * 65536, wlo + (size_t)(9 + i) * 65536,
            whi + (size_t)12 * 65536, wlo + (size_t)12 * 65536,
            xa, xb, xr);
        // fused readout (+ gfc for this conv block)
        k_readout_all<<<G, 256, 0, stream>>>(
            cur, xr, gstart, rd_w + 256 * Dk, rd_b,
            wihT, whhT, gru_bih, gru_bhh, gf,
            mg1_w + (size_t)i * 196608 + 131072, mg1_b + i * Dk, gfc,
            out_ggl + i);
        hipMemsetAsync(nxt, 0, (size_t)N * Dk * 4, stream);
        k_edge_mf<<<NEBLK, 256, 0, stream>>>(
            xa, xb, gfc, src_s, dst_s, gb_s, eperm,
            whi + (size_t)i * 65536, wlo + (size_t)i * 65536, mg2_b + i * Dk,
            whi + (size_t)(3 + i) * 65536, wlo + (size_t)(3 + i) * 65536, gate_b + i * Dk,
            nxt, out_lgl, i);
        float* tmp = cur; cur = nxt; nxt = tmp;
    }
    k_mm_mf<1><<<nblk32, 256, 0, stream>>>(
        cur, N,
        whi + (size_t)12 * 65536, wlo + (size_t)12 * 65536,
        nullptr, nullptr, nullptr, nullptr,
        xr, nullptr, nullptr);
    k_readout_all<<<G, 256, 0, stream>>>(
        cur, xr, gstart, rd_w + 256 * Dk, rd_b,
        wihT, whhT, gru_bih, gru_bhh, gf,
        nullptr, nullptr, nullptr,
        out_ggl + L);

    k_bn<<<1, 256, 0, stream>>>(gf, bn_g, bn_b, xn);
    k_clf1<<<G, 256, 0, stream>>>(xn, clf1_w, clf1_b, hcl);
    k_clf2<<<G, 256, 0, stream>>>(hcl, clf2_w, clf2_b, out_logits);
}